// Round 3
// baseline (4560.500 us; speedup 1.0000x reference)
//
#include <hip/hip_runtime.h>
#include <hip/hip_bf16.h>

#define N_NODES 50000
#define N_EDGES 1600000
#define IN_CH 256
#define NEG_SLOPE 0.2f
#define EPS_F 1e-16f

__device__ __forceinline__ float lrelu(float x) {
    return x > 0.f ? x : NEG_SLOPE * x;
}

// -------- Kernel 0a: detect edge_index storage (int64 vs int32) --------
// int64 values < 50000: int32 view has high word 0 at every odd slot.
__global__ __launch_bounds__(256) void k0_detect(const int* __restrict__ ei,
                                                 int* __restrict__ flag)
{
    __shared__ int nz;
    const int t = threadIdx.x;
    if (t == 0) nz = 0;
    __syncthreads();
    if (t & 1) { if (ei[t] != 0) atomicAdd(&nz, 1); }
    __syncthreads();
    if (t == 0) flag[0] = (nz == 0) ? 1 : 0;   // 1 => int64 layout
}

// -------- Kernel 0b: normalize edge_index to int32 src/dst --------
__global__ __launch_bounds__(256) void k0_repack(const int* __restrict__ ei,
                                                 const int* __restrict__ flag,
                                                 int* __restrict__ srcW,
                                                 int* __restrict__ dstW)
{
    const int e = blockIdx.x * 256 + threadIdx.x;
    if (e >= N_EDGES) return;
    if (flag[0]) {  // int64: pairs (lo,hi); dst row starts at i32 offset 2*N_EDGES
        srcW[e] = ei[2 * (size_t)e];
        dstW[e] = ei[2 * (size_t)N_EDGES + 2 * (size_t)e];
    } else {        // int32
        srcW[e] = ei[e];
        dstW[e] = ei[(size_t)N_EDGES + e];
    }
}

// ---------------- Kernel 1: h1 = x @ W1 ; a_src1/a_dst1 fused ----------------
__global__ __launch_bounds__(256) void k1_gemm1(
    const float* __restrict__ x, const float* __restrict__ W1,
    const float* __restrict__ att_src1, const float* __restrict__ att_dst1,
    float* __restrict__ h1, float* __restrict__ a_src1, float* __restrict__ a_dst1)
{
    __shared__ float w1s[IN_CH * 32];   // 32 KB
    __shared__ float xs[8][IN_CH];      // 8 KB
    __shared__ float attss[32], attds[32];
    const int t = threadIdx.x;
    for (int i = t; i < IN_CH * 32; i += 256) w1s[i] = W1[i];
    if (t < 32) { attss[t] = att_src1[t]; attds[t] = att_dst1[t]; }
    const int row0 = blockIdx.x * 32;
    const int col = t & 31, rl = t >> 5;
    for (int b = 0; b < 4; ++b) {
        const int rbase = row0 + b * 8;
        {   // stage 8 rows of x (float4 vector loads, 8 floats per lane)
            const int r = t >> 5, chunk = t & 31;
            const int row = rbase + r;
            float4 v0 = make_float4(0.f, 0.f, 0.f, 0.f), v1 = v0;
            if (row < N_NODES) {
                const float4* p = (const float4*)(x + (size_t)row * IN_CH + chunk * 8);
                v0 = p[0]; v1 = p[1];
            }
            float* xp = &xs[r][chunk * 8];
            xp[0] = v0.x; xp[1] = v0.y; xp[2] = v0.z; xp[3] = v0.w;
            xp[4] = v1.x; xp[5] = v1.y; xp[6] = v1.z; xp[7] = v1.w;
        }
        __syncthreads();
        const int row = rbase + rl;
        float acc = 0.f;
        #pragma unroll 8
        for (int k = 0; k < IN_CH; ++k)
            acc += xs[rl][k] * w1s[k * 32 + col];
        if (row < N_NODES) h1[(size_t)row * 32 + col] = acc;
        // fused attention logits: reduce over 16 channels of each head
        const int head = col >> 4, c = col & 15;
        float sa = acc * attss[col];
        float sd = acc * attds[col];
        #pragma unroll
        for (int m = 1; m < 16; m <<= 1) {
            sa += __shfl_xor(sa, m);
            sd += __shfl_xor(sd, m);
        }
        if (c == 0 && row < N_NODES) {
            a_src1[row * 2 + head] = sa;
            a_dst1[row * 2 + head] = sd;
        }
        __syncthreads();
    }
}

// ---------------- Kernel 2: layer-1 softmax denominators ----------------
__global__ __launch_bounds__(256) void k2_denom1(
    const int* __restrict__ src, const int* __restrict__ dst,
    const float* __restrict__ a_src1, const float* __restrict__ a_dst1,
    float* __restrict__ denom1)
{
    const int e = blockIdx.x * 256 + threadIdx.x;
    if (e >= N_EDGES) return;
    const int s = src[e], d = dst[e];
    const float2 as = *(const float2*)(a_src1 + 2 * (size_t)s);
    const float2 ad = *(const float2*)(a_dst1 + 2 * (size_t)d);
    const float ex0 = expf(lrelu(as.x + ad.x));
    const float ex1 = expf(lrelu(as.y + ad.y));
    atomicAdd(&denom1[2 * (size_t)d],     ex0);
    atomicAdd(&denom1[2 * (size_t)d + 1], ex1);
}

// ---------------- Kernel 3: layer-1 weighted scatter ----------------
__global__ __launch_bounds__(256) void k3_scatter1(
    const int* __restrict__ src, const int* __restrict__ dst,
    const float* __restrict__ a_src1, const float* __restrict__ a_dst1,
    const float* __restrict__ denom1, const float* __restrict__ h1,
    float* __restrict__ out1)
{
    const int tid = blockIdx.x * 256 + threadIdx.x;
    if (tid >= 2 * N_EDGES) return;
    const int e = tid >> 1, hh = tid & 1;
    const int s = src[e], d = dst[e];
    const float l = a_src1[2 * (size_t)s + hh] + a_dst1[2 * (size_t)d + hh];
    const float alpha = expf(lrelu(l)) / (denom1[2 * (size_t)d + hh] + EPS_F);
    const float4* hp = (const float4*)(h1 + (size_t)s * 32 + hh * 16);
    float* op = out1 + (size_t)d * 32 + hh * 16;
    #pragma unroll
    for (int i = 0; i < 4; ++i) {
        const float4 v = hp[i];
        atomicAdd(op + 4 * i + 0, alpha * v.x);
        atomicAdd(op + 4 * i + 1, alpha * v.y);
        atomicAdd(op + 4 * i + 2, alpha * v.z);
        atomicAdd(op + 4 * i + 3, alpha * v.w);
    }
}

// ---------------- Kernel 4: h2 = elu(out1+b1) @ W2 ; a_src2/a_dst2 fused ----------------
__global__ __launch_bounds__(256) void k4_layer2(
    const float* __restrict__ out1, const float* __restrict__ b1,
    const float* __restrict__ W2, const float* __restrict__ att_src2,
    const float* __restrict__ att_dst2,
    float* __restrict__ h2, float* __restrict__ a_src2, float* __restrict__ a_dst2)
{
    __shared__ float act[16][32];
    __shared__ float w2s[32 * 16];
    __shared__ float b1s[32], as2[16], ad2[16];
    const int t = threadIdx.x;
    for (int i = t; i < 512; i += 256) w2s[i] = W2[i];
    if (t < 32) b1s[t] = b1[t];
    if (t < 16) { as2[t] = att_src2[t]; ad2[t] = att_dst2[t]; }
    __syncthreads();
    const int node0 = blockIdx.x * 16;
    for (int i = t; i < 512; i += 256) {
        const int nl = i >> 5, k = i & 31;
        const int row = node0 + nl;
        float v = 0.f;
        if (row < N_NODES) {
            v = out1[(size_t)row * 32 + k] + b1s[k];
            v = v > 0.f ? v : expm1f(v);   // ELU
        }
        act[nl][k] = v;
    }
    __syncthreads();
    const int nl = t >> 4, j = t & 15;
    const int row = node0 + nl;
    float acc = 0.f;
    #pragma unroll
    for (int k = 0; k < 32; ++k) acc += act[nl][k] * w2s[k * 16 + j];
    if (row < N_NODES) h2[(size_t)row * 16 + j] = acc;
    float sa = acc * as2[j], sd = acc * ad2[j];
    #pragma unroll
    for (int m = 1; m < 16; m <<= 1) { sa += __shfl_xor(sa, m); sd += __shfl_xor(sd, m); }
    if (j == 0 && row < N_NODES) { a_src2[row] = sa; a_dst2[row] = sd; }
}

// ---------------- Kernel 5: layer-2 softmax denominators ----------------
__global__ __launch_bounds__(256) void k5_denom2(
    const int* __restrict__ src, const int* __restrict__ dst,
    const float* __restrict__ a_src2, const float* __restrict__ a_dst2,
    float* __restrict__ denom2)
{
    const int e = blockIdx.x * 256 + threadIdx.x;
    if (e >= N_EDGES) return;
    const int s = src[e], d = dst[e];
    const float ex = expf(lrelu(a_src2[s] + a_dst2[d]));
    atomicAdd(&denom2[d], ex);
}

// ---------------- Kernel 6: layer-2 weighted scatter ----------------
__global__ __launch_bounds__(256) void k6_scatter2(
    const int* __restrict__ src, const int* __restrict__ dst,
    const float* __restrict__ a_src2, const float* __restrict__ a_dst2,
    const float* __restrict__ denom2, const float* __restrict__ h2,
    float* __restrict__ out2)
{
    const int e = blockIdx.x * 256 + threadIdx.x;
    if (e >= N_EDGES) return;
    const int s = src[e], d = dst[e];
    const float l = a_src2[s] + a_dst2[d];
    const float alpha = expf(lrelu(l)) / (denom2[d] + EPS_F);
    const float4* hp = (const float4*)(h2 + (size_t)s * 16);
    float* op = out2 + (size_t)d * 16;
    #pragma unroll
    for (int i = 0; i < 4; ++i) {
        const float4 v = hp[i];
        atomicAdd(op + 4 * i + 0, alpha * v.x);
        atomicAdd(op + 4 * i + 1, alpha * v.y);
        atomicAdd(op + 4 * i + 2, alpha * v.z);
        atomicAdd(op + 4 * i + 3, alpha * v.w);
    }
}

// ---------------- Kernel 7: edge MLP (fp32 in/out) ----------------
__global__ __launch_bounds__(256) void k7_mlp(
    const int* __restrict__ src, const int* __restrict__ dst,
    const float* __restrict__ out2, const float* __restrict__ b2,
    const float* __restrict__ Wm1, const float* __restrict__ bm1,
    const float* __restrict__ Wm2, const float* __restrict__ bm2,
    float* __restrict__ out)
{
    __shared__ float wm1s[32 * 16];
    __shared__ float b2s[16], bm1s[16], wm2s[16];
    __shared__ float bm2s;
    const int t = threadIdx.x;
    for (int i = t; i < 512; i += 256) wm1s[i] = Wm1[i];
    if (t < 16) { b2s[t] = b2[t]; bm1s[t] = bm1[t]; wm2s[t] = Wm2[t]; }
    if (t == 0) bm2s = bm2[0];
    __syncthreads();
    const int e = blockIdx.x * 256 + t;
    if (e >= N_EDGES) return;
    const int s = src[e], d = dst[e];
    float hs[16], hd[16];
    const float4* sp = (const float4*)(out2 + (size_t)s * 16);
    const float4* dp = (const float4*)(out2 + (size_t)d * 16);
    #pragma unroll
    for (int i = 0; i < 4; ++i) {
        const float4 v = sp[i];
        hs[4 * i + 0] = v.x + b2s[4 * i + 0];
        hs[4 * i + 1] = v.y + b2s[4 * i + 1];
        hs[4 * i + 2] = v.z + b2s[4 * i + 2];
        hs[4 * i + 3] = v.w + b2s[4 * i + 3];
        const float4 u = dp[i];
        hd[4 * i + 0] = u.x + b2s[4 * i + 0];
        hd[4 * i + 1] = u.y + b2s[4 * i + 1];
        hd[4 * i + 2] = u.z + b2s[4 * i + 2];
        hd[4 * i + 3] = u.w + b2s[4 * i + 3];
    }
    float fl = bm2s;
    #pragma unroll
    for (int j = 0; j < 16; ++j) {
        float acc = bm1s[j];
        #pragma unroll
        for (int k = 0; k < 16; ++k) {
            acc += hs[k] * wm1s[k * 16 + j];
            acc += hd[k] * wm1s[(16 + k) * 16 + j];
        }
        acc = fmaxf(acc, 0.f);
        fl += acc * wm2s[j];
    }
    fl = fmaxf(fl, 0.f);
    out[e] = fl;
}

extern "C" void kernel_launch(void* const* d_in, const int* in_sizes, int n_in,
                              void* d_out, int out_size, void* d_ws, size_t ws_size,
                              hipStream_t stream)
{
    const float* x        = (const float*)d_in[0];
    const int*   ei       = (const int*)d_in[1];
    const float* W1       = (const float*)d_in[2];
    const float* att_src1 = (const float*)d_in[3];
    const float* att_dst1 = (const float*)d_in[4];
    const float* b1       = (const float*)d_in[5];
    const float* W2       = (const float*)d_in[6];
    const float* att_src2 = (const float*)d_in[7];
    const float* att_dst2 = (const float*)d_in[8];
    const float* b2       = (const float*)d_in[9];
    const float* Wm1      = (const float*)d_in[10];
    const float* bm1      = (const float*)d_in[11];
    const float* Wm2      = (const float*)d_in[12];
    const float* bm2      = (const float*)d_in[13];

    float* ws = (float*)d_ws;
    size_t off = 0;
    float* denom1 = ws + off; off += 2  * (size_t)N_NODES;
    float* out1   = ws + off; off += 32 * (size_t)N_NODES;
    float* denom2 = ws + off; off += 1  * (size_t)N_NODES;
    float* out2   = ws + off; off += 16 * (size_t)N_NODES;
    const size_t zero_floats = off;   // everything above must start at 0
    float* h1     = ws + off; off += 32 * (size_t)N_NODES;
    float* a_src1 = ws + off; off += 2  * (size_t)N_NODES;
    float* a_dst1 = ws + off; off += 2  * (size_t)N_NODES;
    float* h2     = ws + off; off += 16 * (size_t)N_NODES;
    float* a_src2 = ws + off; off += 1  * (size_t)N_NODES;
    float* a_dst2 = ws + off; off += 1  * (size_t)N_NODES;
    int* srcW = (int*)(ws + off); off += (size_t)N_EDGES;
    int* dstW = (int*)(ws + off); off += (size_t)N_EDGES;
    int* flag = (int*)(ws + off); off += 64;

    hipMemsetAsync(d_ws, 0, zero_floats * sizeof(float), stream);

    k0_detect<<<1, 256, 0, stream>>>(ei, flag);
    k0_repack<<<(N_EDGES + 255) / 256, 256, 0, stream>>>(ei, flag, srcW, dstW);

    k1_gemm1<<<(N_NODES + 31) / 32, 256, 0, stream>>>(
        x, W1, att_src1, att_dst1, h1, a_src1, a_dst1);
    k2_denom1<<<(N_EDGES + 255) / 256, 256, 0, stream>>>(
        srcW, dstW, a_src1, a_dst1, denom1);
    k3_scatter1<<<(2 * N_EDGES + 255) / 256, 256, 0, stream>>>(
        srcW, dstW, a_src1, a_dst1, denom1, h1, out1);
    k4_layer2<<<(N_NODES + 15) / 16, 256, 0, stream>>>(
        out1, b1, W2, att_src2, att_dst2, h2, a_src2, a_dst2);
    k5_denom2<<<(N_EDGES + 255) / 256, 256, 0, stream>>>(
        srcW, dstW, a_src2, a_dst2, denom2);
    k6_scatter2<<<(N_EDGES + 255) / 256, 256, 0, stream>>>(
        srcW, dstW, a_src2, a_dst2, denom2, h2, out2);
    k7_mlp<<<(N_EDGES + 255) / 256, 256, 0, stream>>>(
        srcW, dstW, out2, b2, Wm1, bm1, Wm2, bm2, (float*)d_out);
}

// Round 4
// 529.434 us; speedup vs baseline: 8.6139x; 8.6139x over previous
//
#include <hip/hip_runtime.h>
#include <hip/hip_bf16.h>

#define N_NODES 50000
#define N_EDGES 1600000
#define IN_CH 256
#define NEG_SLOPE 0.2f
#define EPS_F 1e-16f

__device__ __forceinline__ float lrelu(float x) {
    return x > 0.f ? x : NEG_SLOPE * x;
}

// -------- Kernel 0a: detect edge_index storage (int64 vs int32) --------
// int64 values < 50000: int32 view has high word 0 at every odd slot.
__global__ __launch_bounds__(256) void k0_detect(const int* __restrict__ ei,
                                                 int* __restrict__ flag)
{
    __shared__ int nz;
    const int t = threadIdx.x;
    if (t == 0) nz = 0;
    __syncthreads();
    if (t & 1) { if (ei[t] != 0) atomicAdd(&nz, 1); }
    __syncthreads();
    if (t == 0) flag[0] = (nz == 0) ? 1 : 0;   // 1 => int64 layout
}

__device__ __forceinline__ int ld_src(const int* ei, int f, int e) {
    return f ? ei[2 * (size_t)e] : ei[e];
}
__device__ __forceinline__ int ld_dst(const int* ei, int f, int e) {
    return f ? ei[2 * (size_t)N_EDGES + 2 * (size_t)e]
             : ei[(size_t)N_EDGES + e];
}

// -------- CSR build step 1: degree count + per-edge slot --------
__global__ __launch_bounds__(256) void k_deg(const int* __restrict__ ei,
                                             const int* __restrict__ flag,
                                             int* __restrict__ deg,
                                             int* __restrict__ eoff)
{
    const int e = blockIdx.x * 256 + threadIdx.x;
    if (e >= N_EDGES) return;
    const int f = flag[0];
    const int d = ld_dst(ei, f, e);
    eoff[e] = atomicAdd(&deg[d], 1);
}

// -------- CSR build step 2: exclusive scan of degrees (single block) --------
__global__ __launch_bounds__(1024) void kscan(const int* __restrict__ deg,
                                              int* __restrict__ rowptr)
{
    __shared__ int sh[1024];
    __shared__ int carry;
    const int t = threadIdx.x;
    if (t == 0) carry = 0;
    __syncthreads();
    for (int base = 0; base < N_NODES; base += 1024) {
        const int i = base + t;
        const int v = (i < N_NODES) ? deg[i] : 0;
        sh[t] = v;
        __syncthreads();
        for (int off = 1; off < 1024; off <<= 1) {
            const int add = (t >= off) ? sh[t - off] : 0;
            __syncthreads();
            sh[t] += add;
            __syncthreads();
        }
        if (i < N_NODES) rowptr[i] = carry + sh[t] - v;   // exclusive
        __syncthreads();
        if (t == 1023) carry += sh[1023];
        __syncthreads();
    }
    if (t == 0) rowptr[N_NODES] = carry;
}

// -------- CSR build step 3: fill (no atomics) --------
__global__ __launch_bounds__(256) void k_fill(const int* __restrict__ ei,
                                              const int* __restrict__ flag,
                                              const int* __restrict__ rowptr,
                                              const int* __restrict__ eoff,
                                              int* __restrict__ csr_src)
{
    const int e = blockIdx.x * 256 + threadIdx.x;
    if (e >= N_EDGES) return;
    const int f = flag[0];
    const int s = ld_src(ei, f, e);
    const int d = ld_dst(ei, f, e);
    csr_src[rowptr[d] + eoff[e]] = s;
}

// ---------------- Kernel 1: h1 = x @ W1 ; a_src1/a_dst1 fused ----------------
__global__ __launch_bounds__(256) void k1_gemm1(
    const float* __restrict__ x, const float* __restrict__ W1,
    const float* __restrict__ att_src1, const float* __restrict__ att_dst1,
    float* __restrict__ h1, float* __restrict__ a_src1, float* __restrict__ a_dst1)
{
    __shared__ float w1s[IN_CH * 32];   // 32 KB
    __shared__ float xs[8][IN_CH];      // 8 KB
    __shared__ float attss[32], attds[32];
    const int t = threadIdx.x;
    for (int i = t; i < IN_CH * 32; i += 256) w1s[i] = W1[i];
    if (t < 32) { attss[t] = att_src1[t]; attds[t] = att_dst1[t]; }
    const int row0 = blockIdx.x * 32;
    const int col = t & 31, rl = t >> 5;
    for (int b = 0; b < 4; ++b) {
        const int rbase = row0 + b * 8;
        {   // stage 8 rows of x
            const int r = t >> 5, chunk = t & 31;
            const int row = rbase + r;
            float4 v0 = make_float4(0.f, 0.f, 0.f, 0.f), v1 = v0;
            if (row < N_NODES) {
                const float4* p = (const float4*)(x + (size_t)row * IN_CH + chunk * 8);
                v0 = p[0]; v1 = p[1];
            }
            float* xp = &xs[r][chunk * 8];
            xp[0] = v0.x; xp[1] = v0.y; xp[2] = v0.z; xp[3] = v0.w;
            xp[4] = v1.x; xp[5] = v1.y; xp[6] = v1.z; xp[7] = v1.w;
        }
        __syncthreads();
        const int row = rbase + rl;
        float acc = 0.f;
        #pragma unroll 8
        for (int k = 0; k < IN_CH; ++k)
            acc += xs[rl][k] * w1s[k * 32 + col];
        if (row < N_NODES) h1[(size_t)row * 32 + col] = acc;
        const int head = col >> 4, c = col & 15;
        float sa = acc * attss[col];
        float sd = acc * attds[col];
        #pragma unroll
        for (int m = 1; m < 16; m <<= 1) {
            sa += __shfl_xor(sa, m);
            sd += __shfl_xor(sd, m);
        }
        if (c == 0 && row < N_NODES) {
            a_src1[row * 2 + head] = sa;
            a_dst1[row * 2 + head] = sd;
        }
        __syncthreads();
    }
}

// -------- Layer-1 aggregation: one wave per dst node, CSR gather --------
__global__ __launch_bounds__(256) void k_agg1(
    const int* __restrict__ rowptr, const int* __restrict__ csr_src,
    const float* __restrict__ a_src1, const float* __restrict__ a_dst1,
    const float* __restrict__ h1, float* __restrict__ out1)
{
    const int wid = (blockIdx.x * 256 + threadIdx.x) >> 6;   // node id
    const int lane = threadIdx.x & 63;
    if (wid >= N_NODES) return;
    const int n = wid;
    const int beg = rowptr[n], end = rowptr[n + 1];
    const float2 ad = *(const float2*)(a_dst1 + 2 * (size_t)n);
    // pass A: softmax denominators (both heads)
    float s0 = 0.f, s1 = 0.f;
    for (int i = beg + lane; i < end; i += 64) {
        const int s = csr_src[i];
        const float2 as = *(const float2*)(a_src1 + 2 * (size_t)s);
        s0 += __expf(lrelu(as.x + ad.x));
        s1 += __expf(lrelu(as.y + ad.y));
    }
    #pragma unroll
    for (int m = 1; m < 64; m <<= 1) {
        s0 += __shfl_xor(s0, m);
        s1 += __shfl_xor(s1, m);
    }
    const float inv0 = 1.f / (s0 + EPS_F), inv1 = 1.f / (s1 + EPS_F);
    // pass B: weighted gather-accumulate; half-wave per edge (32 channels)
    const int slot = lane >> 5, ch = lane & 31;
    const int head = ch >> 4;
    const float inv = head ? inv1 : inv0;
    const float adh = head ? ad.y : ad.x;
    float acc = 0.f;
    for (int i = beg + slot; i < end; i += 2) {
        const int s = csr_src[i];
        const float alpha = __expf(lrelu(a_src1[2 * (size_t)s + head] + adh)) * inv;
        acc += alpha * h1[(size_t)s * 32 + ch];
    }
    acc += __shfl_xor(acc, 32);
    if (lane < 32) out1[(size_t)n * 32 + lane] = acc;
}

// ---------------- Kernel 4: h2 = elu(out1+b1) @ W2 ; a_src2/a_dst2 fused ----------------
__global__ __launch_bounds__(256) void k4_layer2(
    const float* __restrict__ out1, const float* __restrict__ b1,
    const float* __restrict__ W2, const float* __restrict__ att_src2,
    const float* __restrict__ att_dst2,
    float* __restrict__ h2, float* __restrict__ a_src2, float* __restrict__ a_dst2)
{
    __shared__ float act[16][32];
    __shared__ float w2s[32 * 16];
    __shared__ float b1s[32], as2[16], ad2[16];
    const int t = threadIdx.x;
    for (int i = t; i < 512; i += 256) w2s[i] = W2[i];
    if (t < 32) b1s[t] = b1[t];
    if (t < 16) { as2[t] = att_src2[t]; ad2[t] = att_dst2[t]; }
    __syncthreads();
    const int node0 = blockIdx.x * 16;
    for (int i = t; i < 512; i += 256) {
        const int nl = i >> 5, k = i & 31;
        const int row = node0 + nl;
        float v = 0.f;
        if (row < N_NODES) {
            v = out1[(size_t)row * 32 + k] + b1s[k];
            v = v > 0.f ? v : expm1f(v);   // ELU
        }
        act[nl][k] = v;
    }
    __syncthreads();
    const int nl = t >> 4, j = t & 15;
    const int row = node0 + nl;
    float acc = 0.f;
    #pragma unroll
    for (int k = 0; k < 32; ++k) acc += act[nl][k] * w2s[k * 16 + j];
    if (row < N_NODES) h2[(size_t)row * 16 + j] = acc;
    float sa = acc * as2[j], sd = acc * ad2[j];
    #pragma unroll
    for (int m = 1; m < 16; m <<= 1) { sa += __shfl_xor(sa, m); sd += __shfl_xor(sd, m); }
    if (j == 0 && row < N_NODES) { a_src2[row] = sa; a_dst2[row] = sd; }
}

// -------- Layer-2 aggregation: one wave per dst node, CSR gather --------
__global__ __launch_bounds__(256) void k_agg2(
    const int* __restrict__ rowptr, const int* __restrict__ csr_src,
    const float* __restrict__ a_src2, const float* __restrict__ a_dst2,
    const float* __restrict__ h2, float* __restrict__ out2)
{
    const int wid = (blockIdx.x * 256 + threadIdx.x) >> 6;
    const int lane = threadIdx.x & 63;
    if (wid >= N_NODES) return;
    const int n = wid;
    const int beg = rowptr[n], end = rowptr[n + 1];
    const float ad = a_dst2[n];
    float ssum = 0.f;
    for (int i = beg + lane; i < end; i += 64) {
        const int s = csr_src[i];
        ssum += __expf(lrelu(a_src2[s] + ad));
    }
    #pragma unroll
    for (int m = 1; m < 64; m <<= 1) ssum += __shfl_xor(ssum, m);
    const float inv = 1.f / (ssum + EPS_F);
    const int slot = lane >> 4, ch = lane & 15;   // 4 edges in flight
    float acc = 0.f;
    for (int i = beg + slot; i < end; i += 4) {
        const int s = csr_src[i];
        const float alpha = __expf(lrelu(a_src2[s] + ad)) * inv;
        acc += alpha * h2[(size_t)s * 16 + ch];
    }
    acc += __shfl_xor(acc, 16);
    acc += __shfl_xor(acc, 32);
    if (lane < 16) out2[(size_t)n * 16 + lane] = acc;
}

// ---------------- Kernel 7: edge MLP (fp32 in/out) ----------------
__global__ __launch_bounds__(256) void k7_mlp(
    const int* __restrict__ ei, const int* __restrict__ flag,
    const float* __restrict__ out2, const float* __restrict__ b2,
    const float* __restrict__ Wm1, const float* __restrict__ bm1,
    const float* __restrict__ Wm2, const float* __restrict__ bm2,
    float* __restrict__ out)
{
    __shared__ float wm1s[32 * 16];
    __shared__ float b2s[16], bm1s[16], wm2s[16];
    __shared__ float bm2s;
    const int t = threadIdx.x;
    for (int i = t; i < 512; i += 256) wm1s[i] = Wm1[i];
    if (t < 16) { b2s[t] = b2[t]; bm1s[t] = bm1[t]; wm2s[t] = Wm2[t]; }
    if (t == 0) bm2s = bm2[0];
    __syncthreads();
    const int e = blockIdx.x * 256 + t;
    if (e >= N_EDGES) return;
    const int f = flag[0];
    const int s = ld_src(ei, f, e);
    const int d = ld_dst(ei, f, e);
    float hs[16], hd[16];
    const float4* sp = (const float4*)(out2 + (size_t)s * 16);
    const float4* dp = (const float4*)(out2 + (size_t)d * 16);
    #pragma unroll
    for (int i = 0; i < 4; ++i) {
        const float4 v = sp[i];
        hs[4 * i + 0] = v.x + b2s[4 * i + 0];
        hs[4 * i + 1] = v.y + b2s[4 * i + 1];
        hs[4 * i + 2] = v.z + b2s[4 * i + 2];
        hs[4 * i + 3] = v.w + b2s[4 * i + 3];
        const float4 u = dp[i];
        hd[4 * i + 0] = u.x + b2s[4 * i + 0];
        hd[4 * i + 1] = u.y + b2s[4 * i + 1];
        hd[4 * i + 2] = u.z + b2s[4 * i + 2];
        hd[4 * i + 3] = u.w + b2s[4 * i + 3];
    }
    float fl = bm2s;
    #pragma unroll
    for (int j = 0; j < 16; ++j) {
        float acc = bm1s[j];
        #pragma unroll
        for (int k = 0; k < 16; ++k) {
            acc += hs[k] * wm1s[k * 16 + j];
            acc += hd[k] * wm1s[(16 + k) * 16 + j];
        }
        acc = fmaxf(acc, 0.f);
        fl += acc * wm2s[j];
    }
    fl = fmaxf(fl, 0.f);
    out[e] = fl;
}

extern "C" void kernel_launch(void* const* d_in, const int* in_sizes, int n_in,
                              void* d_out, int out_size, void* d_ws, size_t ws_size,
                              hipStream_t stream)
{
    const float* x        = (const float*)d_in[0];
    const int*   ei       = (const int*)d_in[1];
    const float* W1       = (const float*)d_in[2];
    const float* att_src1 = (const float*)d_in[3];
    const float* att_dst1 = (const float*)d_in[4];
    const float* b1       = (const float*)d_in[5];
    const float* W2       = (const float*)d_in[6];
    const float* att_src2 = (const float*)d_in[7];
    const float* att_dst2 = (const float*)d_in[8];
    const float* b2       = (const float*)d_in[9];
    const float* Wm1      = (const float*)d_in[10];
    const float* bm1      = (const float*)d_in[11];
    const float* Wm2      = (const float*)d_in[12];
    const float* bm2      = (const float*)d_in[13];

    // float arrays first (all 16B-aligned), then int arrays
    float* ws = (float*)d_ws;
    size_t off = 0;
    float* h1     = ws + off; off += 32 * (size_t)N_NODES;
    float* a_src1 = ws + off; off += 2  * (size_t)N_NODES;
    float* a_dst1 = ws + off; off += 2  * (size_t)N_NODES;
    float* out1   = ws + off; off += 32 * (size_t)N_NODES;
    float* h2     = ws + off; off += 16 * (size_t)N_NODES;
    float* a_src2 = ws + off; off += 1  * (size_t)N_NODES;
    float* a_dst2 = ws + off; off += 1  * (size_t)N_NODES;
    float* out2   = ws + off; off += 16 * (size_t)N_NODES;
    int* deg     = (int*)(ws + off); off += (size_t)N_NODES;
    int* rowptr  = (int*)(ws + off); off += (size_t)N_NODES + 16;
    int* eoff    = (int*)(ws + off); off += (size_t)N_EDGES;
    int* csr_src = (int*)(ws + off); off += (size_t)N_EDGES;
    int* flag    = (int*)(ws + off); off += 64;

    hipMemsetAsync(deg, 0, (size_t)N_NODES * sizeof(int), stream);

    k0_detect<<<1, 256, 0, stream>>>(ei, flag);
    k_deg<<<(N_EDGES + 255) / 256, 256, 0, stream>>>(ei, flag, deg, eoff);
    kscan<<<1, 1024, 0, stream>>>(deg, rowptr);
    k_fill<<<(N_EDGES + 255) / 256, 256, 0, stream>>>(ei, flag, rowptr, eoff, csr_src);

    k1_gemm1<<<(N_NODES + 31) / 32, 256, 0, stream>>>(
        x, W1, att_src1, att_dst1, h1, a_src1, a_dst1);
    k_agg1<<<(N_NODES + 3) / 4, 256, 0, stream>>>(
        rowptr, csr_src, a_src1, a_dst1, h1, out1);
    k4_layer2<<<(N_NODES + 15) / 16, 256, 0, stream>>>(
        out1, b1, W2, att_src2, att_dst2, h2, a_src2, a_dst2);
    k_agg2<<<(N_NODES + 3) / 4, 256, 0, stream>>>(
        rowptr, csr_src, a_src2, a_dst2, h2, out2);
    k7_mlp<<<(N_EDGES + 255) / 256, 256, 0, stream>>>(
        ei, flag, out2, b2, Wm1, bm1, Wm2, bm2, (float*)d_out);
}

// Round 5
// 448.388 us; speedup vs baseline: 10.1709x; 1.1808x over previous
//
#include <hip/hip_runtime.h>
#include <hip/hip_bf16.h>

#define N_NODES 50000
#define N_EDGES 1600000
#define IN_CH 256
#define NEG_SLOPE 0.2f
#define EPS_F 1e-16f
#define SCAN_BLK 1024
#define N_SCAN_BLKS ((N_NODES + SCAN_BLK - 1) / SCAN_BLK)   // 49

__device__ __forceinline__ float lrelu(float x) {
    return x > 0.f ? x : NEG_SLOPE * x;
}

// -------- Kernel 0a: detect edge_index storage (int64 vs int32) --------
__global__ __launch_bounds__(256) void k0_detect(const int* __restrict__ ei,
                                                 int* __restrict__ flag)
{
    __shared__ int nz;
    const int t = threadIdx.x;
    if (t == 0) nz = 0;
    __syncthreads();
    if (t & 1) { if (ei[t] != 0) atomicAdd(&nz, 1); }
    __syncthreads();
    if (t == 0) flag[0] = (nz == 0) ? 1 : 0;   // 1 => int64 layout
}

__device__ __forceinline__ int ld_src(const int* ei, int f, int e) {
    return f ? ei[2 * (size_t)e] : ei[e];
}
__device__ __forceinline__ int ld_dst(const int* ei, int f, int e) {
    return f ? ei[2 * (size_t)N_EDGES + 2 * (size_t)e]
             : ei[(size_t)N_EDGES + e];
}

// -------- CSR build step 1: degree count + per-edge slot --------
__global__ __launch_bounds__(256) void k_deg(const int* __restrict__ ei,
                                             const int* __restrict__ flag,
                                             int* __restrict__ deg,
                                             int* __restrict__ eoff)
{
    const int e = blockIdx.x * 256 + threadIdx.x;
    if (e >= N_EDGES) return;
    const int f = flag[0];
    const int d = ld_dst(ei, f, e);
    eoff[e] = atomicAdd(&deg[d], 1);
}

// -------- Hierarchical exclusive scan, phase A: per-block scan --------
__global__ __launch_bounds__(SCAN_BLK) void kscanA(const int* __restrict__ deg,
                                                   int* __restrict__ locscan,
                                                   int* __restrict__ blksum)
{
    __shared__ int wsum[SCAN_BLK / 64];
    const int t = threadIdx.x;
    const int i = blockIdx.x * SCAN_BLK + t;
    const int v = (i < N_NODES) ? deg[i] : 0;
    const int lane = t & 63, w = t >> 6;
    int x = v;   // inclusive scan within wave
    #pragma unroll
    for (int off = 1; off < 64; off <<= 1) {
        const int y = __shfl_up(x, off);
        if (lane >= off) x += y;
    }
    if (lane == 63) wsum[w] = x;
    __syncthreads();
    if (t < SCAN_BLK / 64) {   // first wave scans the 16 wave totals
        const int wv = wsum[t];
        int xx = wv;
        #pragma unroll
        for (int off = 1; off < SCAN_BLK / 64; off <<= 1) {
            const int y = __shfl_up(xx, off);
            if (t >= off) xx += y;
        }
        wsum[t] = xx - wv;   // exclusive wave offset
    }
    __syncthreads();
    const int excl = x - v + wsum[w];
    if (i < N_NODES) locscan[i] = excl;
    if (t == SCAN_BLK - 1) blksum[blockIdx.x] = excl + v;   // block total
}

// -------- Phase B: scan the 49 block sums (one wave) --------
__global__ __launch_bounds__(64) void kscanB(const int* __restrict__ blksum,
                                             int* __restrict__ blkoff,
                                             int* __restrict__ rowptr)
{
    const int t = threadIdx.x;
    const int v = (t < N_SCAN_BLKS) ? blksum[t] : 0;
    int x = v;
    #pragma unroll
    for (int off = 1; off < 64; off <<= 1) {
        const int y = __shfl_up(x, off);
        if (t >= off) x += y;
    }
    if (t < N_SCAN_BLKS) blkoff[t] = x - v;
    if (t == 63) rowptr[N_NODES] = x;   // grand total (= N_EDGES)
}

// -------- Phase C: add block offsets --------
__global__ __launch_bounds__(256) void kscanC(const int* __restrict__ locscan,
                                              const int* __restrict__ blkoff,
                                              int* __restrict__ rowptr)
{
    const int i = blockIdx.x * 256 + threadIdx.x;
    if (i < N_NODES) rowptr[i] = locscan[i] + blkoff[i >> 10];
}

// -------- CSR build step 3: fill (no atomics) --------
__global__ __launch_bounds__(256) void k_fill(const int* __restrict__ ei,
                                              const int* __restrict__ flag,
                                              const int* __restrict__ rowptr,
                                              const int* __restrict__ eoff,
                                              int* __restrict__ csr_src)
{
    const int e = blockIdx.x * 256 + threadIdx.x;
    if (e >= N_EDGES) return;
    const int f = flag[0];
    const int s = ld_src(ei, f, e);
    const int d = ld_dst(ei, f, e);
    csr_src[rowptr[d] + eoff[e]] = s;
}

// ---------------- Kernel 1: h1 = x @ W1 ; a_src1/a_dst1 fused ----------------
__global__ __launch_bounds__(256) void k1_gemm1(
    const float* __restrict__ x, const float* __restrict__ W1,
    const float* __restrict__ att_src1, const float* __restrict__ att_dst1,
    float* __restrict__ h1, float* __restrict__ a_src1, float* __restrict__ a_dst1)
{
    __shared__ float w1s[IN_CH * 32];   // 32 KB
    __shared__ float xs[8][IN_CH];      // 8 KB
    __shared__ float attss[32], attds[32];
    const int t = threadIdx.x;
    for (int i = t; i < IN_CH * 32; i += 256) w1s[i] = W1[i];
    if (t < 32) { attss[t] = att_src1[t]; attds[t] = att_dst1[t]; }
    const int row0 = blockIdx.x * 32;
    const int col = t & 31, rl = t >> 5;
    for (int b = 0; b < 4; ++b) {
        const int rbase = row0 + b * 8;
        {
            const int r = t >> 5, chunk = t & 31;
            const int row = rbase + r;
            float4 v0 = make_float4(0.f, 0.f, 0.f, 0.f), v1 = v0;
            if (row < N_NODES) {
                const float4* p = (const float4*)(x + (size_t)row * IN_CH + chunk * 8);
                v0 = p[0]; v1 = p[1];
            }
            float* xp = &xs[r][chunk * 8];
            xp[0] = v0.x; xp[1] = v0.y; xp[2] = v0.z; xp[3] = v0.w;
            xp[4] = v1.x; xp[5] = v1.y; xp[6] = v1.z; xp[7] = v1.w;
        }
        __syncthreads();
        const int row = rbase + rl;
        float acc = 0.f;
        #pragma unroll 8
        for (int k = 0; k < IN_CH; ++k)
            acc += xs[rl][k] * w1s[k * 32 + col];
        if (row < N_NODES) h1[(size_t)row * 32 + col] = acc;
        const int head = col >> 4, c = col & 15;
        float sa = acc * attss[col];
        float sd = acc * attds[col];
        #pragma unroll
        for (int m = 1; m < 16; m <<= 1) {
            sa += __shfl_xor(sa, m);
            sd += __shfl_xor(sd, m);
        }
        if (c == 0 && row < N_NODES) {
            a_src1[row * 2 + head] = sa;
            a_dst1[row * 2 + head] = sd;
        }
        __syncthreads();
    }
}

// -------- Layer-1 aggregation: one wave per dst node, CSR gather --------
__global__ __launch_bounds__(256) void k_agg1(
    const int* __restrict__ rowptr, const int* __restrict__ csr_src,
    const float* __restrict__ a_src1, const float* __restrict__ a_dst1,
    const float* __restrict__ h1, float* __restrict__ out1)
{
    const int wid = (blockIdx.x * 256 + threadIdx.x) >> 6;   // node id
    const int lane = threadIdx.x & 63;
    if (wid >= N_NODES) return;
    const int n = wid;
    const int beg = rowptr[n], end = rowptr[n + 1];
    const float2 ad = *(const float2*)(a_dst1 + 2 * (size_t)n);
    float s0 = 0.f, s1 = 0.f;
    for (int i = beg + lane; i < end; i += 64) {
        const int s = csr_src[i];
        const float2 as = *(const float2*)(a_src1 + 2 * (size_t)s);
        s0 += __expf(lrelu(as.x + ad.x));
        s1 += __expf(lrelu(as.y + ad.y));
    }
    #pragma unroll
    for (int m = 1; m < 64; m <<= 1) {
        s0 += __shfl_xor(s0, m);
        s1 += __shfl_xor(s1, m);
    }
    const float inv0 = 1.f / (s0 + EPS_F), inv1 = 1.f / (s1 + EPS_F);
    const int slot = lane >> 5, ch = lane & 31;
    const int head = ch >> 4;
    const float inv = head ? inv1 : inv0;
    const float adh = head ? ad.y : ad.x;
    float acc = 0.f;
    for (int i = beg + slot; i < end; i += 2) {
        const int s = csr_src[i];
        const float alpha = __expf(lrelu(a_src1[2 * (size_t)s + head] + adh)) * inv;
        acc += alpha * h1[(size_t)s * 32 + ch];
    }
    acc += __shfl_xor(acc, 32);
    if (lane < 32) out1[(size_t)n * 32 + lane] = acc;
}

// ---------------- Kernel 4: h2 = elu(out1+b1) @ W2 ; a_src2/a_dst2 fused ----------------
__global__ __launch_bounds__(256) void k4_layer2(
    const float* __restrict__ out1, const float* __restrict__ b1,
    const float* __restrict__ W2, const float* __restrict__ att_src2,
    const float* __restrict__ att_dst2,
    float* __restrict__ h2, float* __restrict__ a_src2, float* __restrict__ a_dst2)
{
    __shared__ float act[16][32];
    __shared__ float w2s[32 * 16];
    __shared__ float b1s[32], as2[16], ad2[16];
    const int t = threadIdx.x;
    for (int i = t; i < 512; i += 256) w2s[i] = W2[i];
    if (t < 32) b1s[t] = b1[t];
    if (t < 16) { as2[t] = att_src2[t]; ad2[t] = att_dst2[t]; }
    __syncthreads();
    const int node0 = blockIdx.x * 16;
    for (int i = t; i < 512; i += 256) {
        const int nl = i >> 5, k = i & 31;
        const int row = node0 + nl;
        float v = 0.f;
        if (row < N_NODES) {
            v = out1[(size_t)row * 32 + k] + b1s[k];
            v = v > 0.f ? v : expm1f(v);   // ELU
        }
        act[nl][k] = v;
    }
    __syncthreads();
    const int nl = t >> 4, j = t & 15;
    const int row = node0 + nl;
    float acc = 0.f;
    #pragma unroll
    for (int k = 0; k < 32; ++k) acc += act[nl][k] * w2s[k * 16 + j];
    if (row < N_NODES) h2[(size_t)row * 16 + j] = acc;
    float sa = acc * as2[j], sd = acc * ad2[j];
    #pragma unroll
    for (int m = 1; m < 16; m <<= 1) { sa += __shfl_xor(sa, m); sd += __shfl_xor(sd, m); }
    if (j == 0 && row < N_NODES) { a_src2[row] = sa; a_dst2[row] = sd; }
}

// -------- Layer-2 aggregation: one wave per dst node, CSR gather --------
__global__ __launch_bounds__(256) void k_agg2(
    const int* __restrict__ rowptr, const int* __restrict__ csr_src,
    const float* __restrict__ a_src2, const float* __restrict__ a_dst2,
    const float* __restrict__ h2, float* __restrict__ out2)
{
    const int wid = (blockIdx.x * 256 + threadIdx.x) >> 6;
    const int lane = threadIdx.x & 63;
    if (wid >= N_NODES) return;
    const int n = wid;
    const int beg = rowptr[n], end = rowptr[n + 1];
    const float ad = a_dst2[n];
    float ssum = 0.f;
    for (int i = beg + lane; i < end; i += 64) {
        const int s = csr_src[i];
        ssum += __expf(lrelu(a_src2[s] + ad));
    }
    #pragma unroll
    for (int m = 1; m < 64; m <<= 1) ssum += __shfl_xor(ssum, m);
    const float inv = 1.f / (ssum + EPS_F);
    const int slot = lane >> 4, ch = lane & 15;
    float acc = 0.f;
    for (int i = beg + slot; i < end; i += 4) {
        const int s = csr_src[i];
        const float alpha = __expf(lrelu(a_src2[s] + ad)) * inv;
        acc += alpha * h2[(size_t)s * 16 + ch];
    }
    acc += __shfl_xor(acc, 16);
    acc += __shfl_xor(acc, 32);
    if (lane < 16) out2[(size_t)n * 16 + lane] = acc;
}

// ---------------- Kernel 7: edge MLP (fp32 in/out) ----------------
__global__ __launch_bounds__(256) void k7_mlp(
    const int* __restrict__ ei, const int* __restrict__ flag,
    const float* __restrict__ out2, const float* __restrict__ b2,
    const float* __restrict__ Wm1, const float* __restrict__ bm1,
    const float* __restrict__ Wm2, const float* __restrict__ bm2,
    float* __restrict__ out)
{
    __shared__ float wm1s[32 * 16];
    __shared__ float b2s[16], bm1s[16], wm2s[16];
    __shared__ float bm2s;
    const int t = threadIdx.x;
    for (int i = t; i < 512; i += 256) wm1s[i] = Wm1[i];
    if (t < 16) { b2s[t] = b2[t]; bm1s[t] = bm1[t]; wm2s[t] = Wm2[t]; }
    if (t == 0) bm2s = bm2[0];
    __syncthreads();
    const int e = blockIdx.x * 256 + t;
    if (e >= N_EDGES) return;
    const int f = flag[0];
    const int s = ld_src(ei, f, e);
    const int d = ld_dst(ei, f, e);
    float hs[16], hd[16];
    const float4* sp = (const float4*)(out2 + (size_t)s * 16);
    const float4* dp = (const float4*)(out2 + (size_t)d * 16);
    #pragma unroll
    for (int i = 0; i < 4; ++i) {
        const float4 v = sp[i];
        hs[4 * i + 0] = v.x + b2s[4 * i + 0];
        hs[4 * i + 1] = v.y + b2s[4 * i + 1];
        hs[4 * i + 2] = v.z + b2s[4 * i + 2];
        hs[4 * i + 3] = v.w + b2s[4 * i + 3];
        const float4 u = dp[i];
        hd[4 * i + 0] = u.x + b2s[4 * i + 0];
        hd[4 * i + 1] = u.y + b2s[4 * i + 1];
        hd[4 * i + 2] = u.z + b2s[4 * i + 2];
        hd[4 * i + 3] = u.w + b2s[4 * i + 3];
    }
    float fl = bm2s;
    #pragma unroll
    for (int j = 0; j < 16; ++j) {
        float acc = bm1s[j];
        #pragma unroll
        for (int k = 0; k < 16; ++k) {
            acc += hs[k] * wm1s[k * 16 + j];
            acc += hd[k] * wm1s[(16 + k) * 16 + j];
        }
        acc = fmaxf(acc, 0.f);
        fl += acc * wm2s[j];
    }
    fl = fmaxf(fl, 0.f);
    out[e] = fl;
}

extern "C" void kernel_launch(void* const* d_in, const int* in_sizes, int n_in,
                              void* d_out, int out_size, void* d_ws, size_t ws_size,
                              hipStream_t stream)
{
    const float* x        = (const float*)d_in[0];
    const int*   ei       = (const int*)d_in[1];
    const float* W1       = (const float*)d_in[2];
    const float* att_src1 = (const float*)d_in[3];
    const float* att_dst1 = (const float*)d_in[4];
    const float* b1       = (const float*)d_in[5];
    const float* W2       = (const float*)d_in[6];
    const float* att_src2 = (const float*)d_in[7];
    const float* att_dst2 = (const float*)d_in[8];
    const float* b2       = (const float*)d_in[9];
    const float* Wm1      = (const float*)d_in[10];
    const float* bm1      = (const float*)d_in[11];
    const float* Wm2      = (const float*)d_in[12];
    const float* bm2      = (const float*)d_in[13];

    float* ws = (float*)d_ws;
    size_t off = 0;
    float* h1     = ws + off; off += 32 * (size_t)N_NODES;
    float* a_src1 = ws + off; off += 2  * (size_t)N_NODES;
    float* a_dst1 = ws + off; off += 2  * (size_t)N_NODES;
    float* out1   = ws + off; off += 32 * (size_t)N_NODES;
    float* h2     = ws + off; off += 16 * (size_t)N_NODES;
    float* a_src2 = ws + off; off += 1  * (size_t)N_NODES;
    float* a_dst2 = ws + off; off += 1  * (size_t)N_NODES;
    float* out2   = ws + off; off += 16 * (size_t)N_NODES;
    int* deg     = (int*)(ws + off); off += (size_t)N_NODES;
    int* locscan = (int*)(ws + off); off += (size_t)N_NODES;
    int* rowptr  = (int*)(ws + off); off += (size_t)N_NODES + 16;
    int* eoff    = (int*)(ws + off); off += (size_t)N_EDGES;
    int* csr_src = (int*)(ws + off); off += (size_t)N_EDGES;
    int* blksum  = (int*)(ws + off); off += 64;
    int* blkoff  = (int*)(ws + off); off += 64;
    int* flag    = (int*)(ws + off); off += 64;

    hipMemsetAsync(deg, 0, (size_t)N_NODES * sizeof(int), stream);

    k0_detect<<<1, 256, 0, stream>>>(ei, flag);
    k_deg<<<(N_EDGES + 255) / 256, 256, 0, stream>>>(ei, flag, deg, eoff);
    kscanA<<<N_SCAN_BLKS, SCAN_BLK, 0, stream>>>(deg, locscan, blksum);
    kscanB<<<1, 64, 0, stream>>>(blksum, blkoff, rowptr);
    kscanC<<<(N_NODES + 255) / 256, 256, 0, stream>>>(locscan, blkoff, rowptr);
    k_fill<<<(N_EDGES + 255) / 256, 256, 0, stream>>>(ei, flag, rowptr, eoff, csr_src);

    k1_gemm1<<<(N_NODES + 31) / 32, 256, 0, stream>>>(
        x, W1, att_src1, att_dst1, h1, a_src1, a_dst1);
    k_agg1<<<(N_NODES + 3) / 4, 256, 0, stream>>>(
        rowptr, csr_src, a_src1, a_dst1, h1, out1);
    k4_layer2<<<(N_NODES + 15) / 16, 256, 0, stream>>>(
        out1, b1, W2, att_src2, att_dst2, h2, a_src2, a_dst2);
    k_agg2<<<(N_NODES + 3) / 4, 256, 0, stream>>>(
        rowptr, csr_src, a_src2, a_dst2, h2, out2);
    k7_mlp<<<(N_EDGES + 255) / 256, 256, 0, stream>>>(
        ei, flag, out2, b2, Wm1, bm1, Wm2, bm2, (float*)d_out);
}

// Round 7
// 443.867 us; speedup vs baseline: 10.2745x; 1.0102x over previous
//
#include <hip/hip_runtime.h>
#include <hip/hip_bf16.h>

#define N_NODES 50000
#define N_EDGES 1600000
#define IN_CH 256
#define NEG_SLOPE 0.2f
#define EPS_F 1e-16f
#define SCAN_BLK 1024
#define N_SCAN_BLKS ((N_NODES + SCAN_BLK - 1) / SCAN_BLK)   // 49

__device__ __forceinline__ float lrelu(float x) {
    return x > 0.f ? x : NEG_SLOPE * x;
}

// -------- Kernel 0a: detect edge_index storage (int64 vs int32) --------
__global__ __launch_bounds__(256) void k0_detect(const int* __restrict__ ei,
                                                 int* __restrict__ flag)
{
    __shared__ int nz;
    const int t = threadIdx.x;
    if (t == 0) nz = 0;
    __syncthreads();
    if (t & 1) { if (ei[t] != 0) atomicAdd(&nz, 1); }
    __syncthreads();
    if (t == 0) flag[0] = (nz == 0) ? 1 : 0;   // 1 => int64 layout
}

__device__ __forceinline__ int ld_src(const int* ei, int f, int e) {
    return f ? ei[2 * (size_t)e] : ei[e];
}
__device__ __forceinline__ int ld_dst(const int* ei, int f, int e) {
    return f ? ei[2 * (size_t)N_EDGES + 2 * (size_t)e]
             : ei[(size_t)N_EDGES + e];
}

// -------- CSR build step 1: degree count + per-edge slot --------
__global__ __launch_bounds__(256) void k_deg(const int* __restrict__ ei,
                                             const int* __restrict__ flag,
                                             int* __restrict__ deg,
                                             int* __restrict__ eoff)
{
    const int e = blockIdx.x * 256 + threadIdx.x;
    if (e >= N_EDGES) return;
    const int f = flag[0];
    const int d = ld_dst(ei, f, e);
    eoff[e] = atomicAdd(&deg[d], 1);
}

// -------- Hierarchical exclusive scan, phase A --------
__global__ __launch_bounds__(SCAN_BLK) void kscanA(const int* __restrict__ deg,
                                                   int* __restrict__ locscan,
                                                   int* __restrict__ blksum)
{
    __shared__ int wsum[SCAN_BLK / 64];
    const int t = threadIdx.x;
    const int i = blockIdx.x * SCAN_BLK + t;
    const int v = (i < N_NODES) ? deg[i] : 0;
    const int lane = t & 63, w = t >> 6;
    int x = v;
    #pragma unroll
    for (int off = 1; off < 64; off <<= 1) {
        const int y = __shfl_up(x, off);
        if (lane >= off) x += y;
    }
    if (lane == 63) wsum[w] = x;
    __syncthreads();
    if (t < SCAN_BLK / 64) {
        const int wv = wsum[t];
        int xx = wv;
        #pragma unroll
        for (int off = 1; off < SCAN_BLK / 64; off <<= 1) {
            const int y = __shfl_up(xx, off);
            if (t >= off) xx += y;
        }
        wsum[t] = xx - wv;
    }
    __syncthreads();
    const int excl = x - v + wsum[w];
    if (i < N_NODES) locscan[i] = excl;
    if (t == SCAN_BLK - 1) blksum[blockIdx.x] = excl + v;
}

// -------- Phase B: scan block sums (one wave) --------
__global__ __launch_bounds__(64) void kscanB(const int* __restrict__ blksum,
                                             int* __restrict__ blkoff,
                                             int* __restrict__ rowptr)
{
    const int t = threadIdx.x;
    const int v = (t < N_SCAN_BLKS) ? blksum[t] : 0;
    int x = v;
    #pragma unroll
    for (int off = 1; off < 64; off <<= 1) {
        const int y = __shfl_up(x, off);
        if (t >= off) x += y;
    }
    if (t < N_SCAN_BLKS) blkoff[t] = x - v;
    if (t == 63) rowptr[N_NODES] = x;
}

// -------- Phase C: add block offsets --------
__global__ __launch_bounds__(256) void kscanC(const int* __restrict__ locscan,
                                              const int* __restrict__ blkoff,
                                              int* __restrict__ rowptr)
{
    const int i = blockIdx.x * 256 + threadIdx.x;
    if (i < N_NODES) rowptr[i] = locscan[i] + blkoff[i >> 10];
}

// -------- CSR build step 3: fill (no atomics) --------
__global__ __launch_bounds__(256) void k_fill(const int* __restrict__ ei,
                                              const int* __restrict__ flag,
                                              const int* __restrict__ rowptr,
                                              const int* __restrict__ eoff,
                                              int* __restrict__ csr_src)
{
    const int e = blockIdx.x * 256 + threadIdx.x;
    if (e >= N_EDGES) return;
    const int f = flag[0];
    const int s = ld_src(ei, f, e);
    const int d = ld_dst(ei, f, e);
    csr_src[rowptr[d] + eoff[e]] = s;
}

// ---------------- Kernel 1: h1 = x @ W1 ; a_src1/a_dst1 fused ----------------
// (R5-exact, proven)
__global__ __launch_bounds__(256) void k1_gemm1(
    const float* __restrict__ x, const float* __restrict__ W1,
    const float* __restrict__ att_src1, const float* __restrict__ att_dst1,
    float* __restrict__ h1, float* __restrict__ a_src1, float* __restrict__ a_dst1)
{
    __shared__ float w1s[IN_CH * 32];   // 32 KB
    __shared__ float xs[8][IN_CH];      // 8 KB
    __shared__ float attss[32], attds[32];
    const int t = threadIdx.x;
    for (int i = t; i < IN_CH * 32; i += 256) w1s[i] = W1[i];
    if (t < 32) { attss[t] = att_src1[t]; attds[t] = att_dst1[t]; }
    const int row0 = blockIdx.x * 32;
    const int col = t & 31, rl = t >> 5;
    for (int b = 0; b < 4; ++b) {
        const int rbase = row0 + b * 8;
        {
            const int r = t >> 5, chunk = t & 31;
            const int row = rbase + r;
            float4 v0 = make_float4(0.f, 0.f, 0.f, 0.f), v1 = v0;
            if (row < N_NODES) {
                const float4* p = (const float4*)(x + (size_t)row * IN_CH + chunk * 8);
                v0 = p[0]; v1 = p[1];
            }
            float* xp = &xs[r][chunk * 8];
            xp[0] = v0.x; xp[1] = v0.y; xp[2] = v0.z; xp[3] = v0.w;
            xp[4] = v1.x; xp[5] = v1.y; xp[6] = v1.z; xp[7] = v1.w;
        }
        __syncthreads();
        const int row = rbase + rl;
        float acc = 0.f;
        #pragma unroll 8
        for (int k = 0; k < IN_CH; ++k)
            acc += xs[rl][k] * w1s[k * 32 + col];
        if (row < N_NODES) h1[(size_t)row * 32 + col] = acc;
        const int head = col >> 4, c = col & 15;
        float sa = acc * attss[col];
        float sd = acc * attds[col];
        #pragma unroll
        for (int m = 1; m < 16; m <<= 1) {
            sa += __shfl_xor(sa, m);
            sd += __shfl_xor(sd, m);
        }
        if (c == 0 && row < N_NODES) {
            a_src1[row * 2 + head] = sa;
            a_dst1[row * 2 + head] = sd;
        }
        __syncthreads();
    }
}

// -------- Layer-1 aggregation: R5 pass-B loop + deferred normalization --------
__global__ __launch_bounds__(256) void k_agg1(
    const int* __restrict__ rowptr, const int* __restrict__ csr_src,
    const float* __restrict__ a_src1, const float* __restrict__ a_dst1,
    const float* __restrict__ h1, float* __restrict__ out1)
{
    const int wid = (blockIdx.x * 256 + threadIdx.x) >> 6;   // node id (wave-uniform)
    const int lane = threadIdx.x & 63;
    if (wid >= N_NODES) return;
    const int beg = rowptr[wid], end = rowptr[wid + 1];
    const float2 ad = *(const float2*)(a_dst1 + 2 * (size_t)wid);
    const int slot = lane >> 5, ch = lane & 31;
    const int head = ch >> 4;
    const float adh = head ? ad.y : ad.x;
    float acc = 0.f, sw = 0.f;
    for (int i = beg + slot; i < end; i += 2) {      // 2 edges in flight (halves)
        const int s = csr_src[i];
        const float w = __expf(lrelu(a_src1[2 * (size_t)s + head] + adh));
        if ((ch & 15) == 0) sw += w;   // one rep lane per (half, head) counts denom
        acc += w * h1[(size_t)s * 32 + ch];          // 128B row gather
    }
    // denom: combine even/odd halves per head (reps at lanes 0,16,32,48)
    sw += __shfl_xor(sw, 32);                    // lane0+=lane32, lane16+=lane48
    const float swh = __shfl(sw, head << 4);     // head0 <- lane0, head1 <- lane16
    acc += __shfl_xor(acc, 32);
    const float inv = 1.f / (swh + EPS_F);
    if (lane < 32) out1[(size_t)wid * 32 + lane] = acc * inv;
}

// ---------------- Kernel 4: h2 = elu(out1+b1) @ W2 ; a_src2/a_dst2 fused ----------------
__global__ __launch_bounds__(256) void k4_layer2(
    const float* __restrict__ out1, const float* __restrict__ b1,
    const float* __restrict__ W2, const float* __restrict__ att_src2,
    const float* __restrict__ att_dst2,
    float* __restrict__ h2, float* __restrict__ a_src2, float* __restrict__ a_dst2)
{
    __shared__ float act[16][32];
    __shared__ float w2s[32 * 16];
    __shared__ float b1s[32], as2[16], ad2[16];
    const int t = threadIdx.x;
    for (int i = t; i < 512; i += 256) w2s[i] = W2[i];
    if (t < 32) b1s[t] = b1[t];
    if (t < 16) { as2[t] = att_src2[t]; ad2[t] = att_dst2[t]; }
    __syncthreads();
    const int node0 = blockIdx.x * 16;
    for (int i = t; i < 512; i += 256) {
        const int nl = i >> 5, k = i & 31;
        const int row = node0 + nl;
        float v = 0.f;
        if (row < N_NODES) {
            v = out1[(size_t)row * 32 + k] + b1s[k];
            v = v > 0.f ? v : expm1f(v);
        }
        act[nl][k] = v;
    }
    __syncthreads();
    const int nl = t >> 4, j = t & 15;
    const int row = node0 + nl;
    float acc = 0.f;
    #pragma unroll
    for (int k = 0; k < 32; ++k) acc += act[nl][k] * w2s[k * 16 + j];
    if (row < N_NODES) h2[(size_t)row * 16 + j] = acc;
    float sa = acc * as2[j], sd = acc * ad2[j];
    #pragma unroll
    for (int m = 1; m < 16; m <<= 1) { sa += __shfl_xor(sa, m); sd += __shfl_xor(sd, m); }
    if (j == 0 && row < N_NODES) { a_src2[row] = sa; a_dst2[row] = sd; }
}

// -------- Layer-2 aggregation: R5 pass-B loop + deferred normalization --------
__global__ __launch_bounds__(256) void k_agg2(
    const int* __restrict__ rowptr, const int* __restrict__ csr_src,
    const float* __restrict__ a_src2, const float* __restrict__ a_dst2,
    const float* __restrict__ h2, float* __restrict__ out2)
{
    const int wid = (blockIdx.x * 256 + threadIdx.x) >> 6;
    const int lane = threadIdx.x & 63;
    if (wid >= N_NODES) return;
    const int beg = rowptr[wid], end = rowptr[wid + 1];
    const float ad = a_dst2[wid];
    const int slot = lane >> 4, ch = lane & 15;
    float acc = 0.f, sw = 0.f;
    for (int i = beg + slot; i < end; i += 4) {      // 4 edges in flight (quarters)
        const int s = csr_src[i];
        const float w = __expf(lrelu(a_src2[s] + ad));
        if (ch == 0) sw += w;          // one rep lane per quarter counts denom
        acc += w * h2[(size_t)s * 16 + ch];          // 64B row gather
    }
    // denom: reps at lanes 0,16,32,48 hold quarter partials, others 0 —
    // full butterfly gives the total on every lane
    #pragma unroll
    for (int m = 1; m < 64; m <<= 1) sw += __shfl_xor(sw, m);
    acc += __shfl_xor(acc, 16);
    acc += __shfl_xor(acc, 32);
    const float inv = 1.f / (sw + EPS_F);
    if (lane < 16) out2[(size_t)wid * 16 + lane] = acc * inv;
}

// ---------------- Kernel 7: edge MLP (fp32 in/out) ----------------
__global__ __launch_bounds__(256) void k7_mlp(
    const int* __restrict__ ei, const int* __restrict__ flag,
    const float* __restrict__ out2, const float* __restrict__ b2,
    const float* __restrict__ Wm1, const float* __restrict__ bm1,
    const float* __restrict__ Wm2, const float* __restrict__ bm2,
    float* __restrict__ out)
{
    __shared__ float wm1s[32 * 16];
    __shared__ float b2s[16], bm1s[16], wm2s[16];
    __shared__ float bm2s;
    const int t = threadIdx.x;
    for (int i = t; i < 512; i += 256) wm1s[i] = Wm1[i];
    if (t < 16) { b2s[t] = b2[t]; bm1s[t] = bm1[t]; wm2s[t] = Wm2[t]; }
    if (t == 0) bm2s = bm2[0];
    __syncthreads();
    const int e = blockIdx.x * 256 + t;
    if (e >= N_EDGES) return;
    const int f = flag[0];
    const int s = ld_src(ei, f, e);
    const int d = ld_dst(ei, f, e);
    float hs[16], hd[16];
    const float4* sp = (const float4*)(out2 + (size_t)s * 16);
    const float4* dp = (const float4*)(out2 + (size_t)d * 16);
    #pragma unroll
    for (int i = 0; i < 4; ++i) {
        const float4 v = sp[i];
        hs[4 * i + 0] = v.x + b2s[4 * i + 0];
        hs[4 * i + 1] = v.y + b2s[4 * i + 1];
        hs[4 * i + 2] = v.z + b2s[4 * i + 2];
        hs[4 * i + 3] = v.w + b2s[4 * i + 3];
        const float4 u = dp[i];
        hd[4 * i + 0] = u.x + b2s[4 * i + 0];
        hd[4 * i + 1] = u.y + b2s[4 * i + 1];
        hd[4 * i + 2] = u.z + b2s[4 * i + 2];
        hd[4 * i + 3] = u.w + b2s[4 * i + 3];
    }
    float fl = bm2s;
    #pragma unroll
    for (int j = 0; j < 16; ++j) {
        float acc = bm1s[j];
        #pragma unroll
        for (int k = 0; k < 16; ++k) {
            acc += hs[k] * wm1s[k * 16 + j];
            acc += hd[k] * wm1s[(16 + k) * 16 + j];
        }
        acc = fmaxf(acc, 0.f);
        fl += acc * wm2s[j];
    }
    fl = fmaxf(fl, 0.f);
    out[e] = fl;
}

extern "C" void kernel_launch(void* const* d_in, const int* in_sizes, int n_in,
                              void* d_out, int out_size, void* d_ws, size_t ws_size,
                              hipStream_t stream)
{
    const float* x        = (const float*)d_in[0];
    const int*   ei       = (const int*)d_in[1];
    const float* W1       = (const float*)d_in[2];
    const float* att_src1 = (const float*)d_in[3];
    const float* att_dst1 = (const float*)d_in[4];
    const float* b1       = (const float*)d_in[5];
    const float* W2       = (const float*)d_in[6];
    const float* att_src2 = (const float*)d_in[7];
    const float* att_dst2 = (const float*)d_in[8];
    const float* b2       = (const float*)d_in[9];
    const float* Wm1      = (const float*)d_in[10];
    const float* bm1      = (const float*)d_in[11];
    const float* Wm2      = (const float*)d_in[12];
    const float* bm2      = (const float*)d_in[13];

    float* ws = (float*)d_ws;
    size_t off = 0;
    float* h1     = ws + off; off += 32 * (size_t)N_NODES;
    float* a_src1 = ws + off; off += 2  * (size_t)N_NODES;
    float* a_dst1 = ws + off; off += 2  * (size_t)N_NODES;
    float* out1   = ws + off; off += 32 * (size_t)N_NODES;
    float* h2     = ws + off; off += 16 * (size_t)N_NODES;
    float* a_src2 = ws + off; off += 1  * (size_t)N_NODES;
    float* a_dst2 = ws + off; off += 1  * (size_t)N_NODES;
    float* out2   = ws + off; off += 16 * (size_t)N_NODES;
    int* deg     = (int*)(ws + off); off += (size_t)N_NODES;
    int* locscan = (int*)(ws + off); off += (size_t)N_NODES;
    int* rowptr  = (int*)(ws + off); off += (size_t)N_NODES + 16;
    int* eoff    = (int*)(ws + off); off += (size_t)N_EDGES;
    int* csr_src = (int*)(ws + off); off += (size_t)N_EDGES;
    int* blksum  = (int*)(ws + off); off += 64;
    int* blkoff  = (int*)(ws + off); off += 64;
    int* flag    = (int*)(ws + off); off += 64;

    hipMemsetAsync(deg, 0, (size_t)N_NODES * sizeof(int), stream);

    k0_detect<<<1, 256, 0, stream>>>(ei, flag);
    k_deg<<<(N_EDGES + 255) / 256, 256, 0, stream>>>(ei, flag, deg, eoff);
    kscanA<<<N_SCAN_BLKS, SCAN_BLK, 0, stream>>>(deg, locscan, blksum);
    kscanB<<<1, 64, 0, stream>>>(blksum, blkoff, rowptr);
    kscanC<<<(N_NODES + 255) / 256, 256, 0, stream>>>(locscan, blkoff, rowptr);
    k_fill<<<(N_EDGES + 255) / 256, 256, 0, stream>>>(ei, flag, rowptr, eoff, csr_src);

    k1_gemm1<<<(N_NODES + 31) / 32, 256, 0, stream>>>(
        x, W1, att_src1, att_dst1, h1, a_src1, a_dst1);
    k_agg1<<<(N_NODES + 3) / 4, 256, 0, stream>>>(
        rowptr, csr_src, a_src1, a_dst1, h1, out1);
    k4_layer2<<<(N_NODES + 15) / 16, 256, 0, stream>>>(
        out1, b1, W2, att_src2, att_dst2, h2, a_src2, a_dst2);
    k_agg2<<<(N_NODES + 3) / 4, 256, 0, stream>>>(
        rowptr, csr_src, a_src2, a_dst2, h2, out2);
    k7_mlp<<<(N_EDGES + 255) / 256, 256, 0, stream>>>(
        ei, flag, out2, b2, Wm1, bm1, Wm2, bm2, (float*)d_out);
}

// Round 8
// 386.715 us; speedup vs baseline: 11.7929x; 1.1478x over previous
//
#include <hip/hip_runtime.h>
#include <hip/hip_bf16.h>

#define N_NODES 50000
#define N_EDGES 1600000
#define IN_CH 256
#define NEG_SLOPE 0.2f
#define EPS_F 1e-16f
#define SCAN_BLK 1024
#define N_SCAN_BLKS ((N_NODES + SCAN_BLK - 1) / SCAN_BLK)   // 49

__device__ __forceinline__ float lrelu(float x) {
    return x > 0.f ? x : NEG_SLOPE * x;
}

// -------- Kernel 0a: detect edge_index storage (int64 vs int32) --------
__global__ __launch_bounds__(256) void k0_detect(const int* __restrict__ ei,
                                                 int* __restrict__ flag)
{
    __shared__ int nz;
    const int t = threadIdx.x;
    if (t == 0) nz = 0;
    __syncthreads();
    if (t & 1) { if (ei[t] != 0) atomicAdd(&nz, 1); }
    __syncthreads();
    if (t == 0) flag[0] = (nz == 0) ? 1 : 0;   // 1 => int64 layout
}

__device__ __forceinline__ int ld_src(const int* ei, int f, int e) {
    return f ? ei[2 * (size_t)e] : ei[e];
}
__device__ __forceinline__ int ld_dst(const int* ei, int f, int e) {
    return f ? ei[2 * (size_t)N_EDGES + 2 * (size_t)e]
             : ei[(size_t)N_EDGES + e];
}

// -------- CSR build step 1: degree count + per-edge slot --------
__global__ __launch_bounds__(256) void k_deg(const int* __restrict__ ei,
                                             const int* __restrict__ flag,
                                             int* __restrict__ deg,
                                             int* __restrict__ eoff)
{
    const int e = blockIdx.x * 256 + threadIdx.x;
    if (e >= N_EDGES) return;
    const int f = flag[0];
    const int d = ld_dst(ei, f, e);
    eoff[e] = atomicAdd(&deg[d], 1);
}

// -------- Hierarchical exclusive scan, phase A --------
__global__ __launch_bounds__(SCAN_BLK) void kscanA(const int* __restrict__ deg,
                                                   int* __restrict__ locscan,
                                                   int* __restrict__ blksum)
{
    __shared__ int wsum[SCAN_BLK / 64];
    const int t = threadIdx.x;
    const int i = blockIdx.x * SCAN_BLK + t;
    const int v = (i < N_NODES) ? deg[i] : 0;
    const int lane = t & 63, w = t >> 6;
    int x = v;
    #pragma unroll
    for (int off = 1; off < 64; off <<= 1) {
        const int y = __shfl_up(x, off);
        if (lane >= off) x += y;
    }
    if (lane == 63) wsum[w] = x;
    __syncthreads();
    if (t < SCAN_BLK / 64) {
        const int wv = wsum[t];
        int xx = wv;
        #pragma unroll
        for (int off = 1; off < SCAN_BLK / 64; off <<= 1) {
            const int y = __shfl_up(xx, off);
            if (t >= off) xx += y;
        }
        wsum[t] = xx - wv;
    }
    __syncthreads();
    const int excl = x - v + wsum[w];
    if (i < N_NODES) locscan[i] = excl;
    if (t == SCAN_BLK - 1) blksum[blockIdx.x] = excl + v;
}

// -------- Phase B: scan block sums (one wave) --------
__global__ __launch_bounds__(64) void kscanB(const int* __restrict__ blksum,
                                             int* __restrict__ blkoff,
                                             int* __restrict__ rowptr)
{
    const int t = threadIdx.x;
    const int v = (t < N_SCAN_BLKS) ? blksum[t] : 0;
    int x = v;
    #pragma unroll
    for (int off = 1; off < 64; off <<= 1) {
        const int y = __shfl_up(x, off);
        if (t >= off) x += y;
    }
    if (t < N_SCAN_BLKS) blkoff[t] = x - v;
    if (t == 63) rowptr[N_NODES] = x;
}

// -------- Phase C: add block offsets --------
__global__ __launch_bounds__(256) void kscanC(const int* __restrict__ locscan,
                                              const int* __restrict__ blkoff,
                                              int* __restrict__ rowptr)
{
    const int i = blockIdx.x * 256 + threadIdx.x;
    if (i < N_NODES) rowptr[i] = locscan[i] + blkoff[i >> 10];
}

// -------- CSR build step 3: fill (no atomics) --------
__global__ __launch_bounds__(256) void k_fill(const int* __restrict__ ei,
                                              const int* __restrict__ flag,
                                              const int* __restrict__ rowptr,
                                              const int* __restrict__ eoff,
                                              int* __restrict__ csr_src)
{
    const int e = blockIdx.x * 256 + threadIdx.x;
    if (e >= N_EDGES) return;
    const int f = flag[0];
    const int s = ld_src(ei, f, e);
    const int d = ld_dst(ei, f, e);
    csr_src[rowptr[d] + eoff[e]] = s;
}

// ---------------- Kernel 1: h1 = x @ W1 ; a_src1/a_dst1 fused ----------------
// (R5-exact, proven)
__global__ __launch_bounds__(256) void k1_gemm1(
    const float* __restrict__ x, const float* __restrict__ W1,
    const float* __restrict__ att_src1, const float* __restrict__ att_dst1,
    float* __restrict__ h1, float* __restrict__ a_src1, float* __restrict__ a_dst1)
{
    __shared__ float w1s[IN_CH * 32];   // 32 KB
    __shared__ float xs[8][IN_CH];      // 8 KB
    __shared__ float attss[32], attds[32];
    const int t = threadIdx.x;
    for (int i = t; i < IN_CH * 32; i += 256) w1s[i] = W1[i];
    if (t < 32) { attss[t] = att_src1[t]; attds[t] = att_dst1[t]; }
    const int row0 = blockIdx.x * 32;
    const int col = t & 31, rl = t >> 5;
    for (int b = 0; b < 4; ++b) {
        const int rbase = row0 + b * 8;
        {
            const int r = t >> 5, chunk = t & 31;
            const int row = rbase + r;
            float4 v0 = make_float4(0.f, 0.f, 0.f, 0.f), v1 = v0;
            if (row < N_NODES) {
                const float4* p = (const float4*)(x + (size_t)row * IN_CH + chunk * 8);
                v0 = p[0]; v1 = p[1];
            }
            float* xp = &xs[r][chunk * 8];
            xp[0] = v0.x; xp[1] = v0.y; xp[2] = v0.z; xp[3] = v0.w;
            xp[4] = v1.x; xp[5] = v1.y; xp[6] = v1.z; xp[7] = v1.w;
        }
        __syncthreads();
        const int row = rbase + rl;
        float acc = 0.f;
        #pragma unroll 8
        for (int k = 0; k < IN_CH; ++k)
            acc += xs[rl][k] * w1s[k * 32 + col];
        if (row < N_NODES) h1[(size_t)row * 32 + col] = acc;
        const int head = col >> 4, c = col & 15;
        float sa = acc * attss[col];
        float sd = acc * attds[col];
        #pragma unroll
        for (int m = 1; m < 16; m <<= 1) {
            sa += __shfl_xor(sa, m);
            sd += __shfl_xor(sd, m);
        }
        if (c == 0 && row < N_NODES) {
            a_src1[row * 2 + head] = sa;
            a_dst1[row * 2 + head] = sd;
        }
        __syncthreads();
    }
}

// -------- Layer-1 aggregation: deferred norm + 4-way MLP unroll --------
__global__ __launch_bounds__(256) void k_agg1(
    const int* __restrict__ rowptr, const int* __restrict__ csr_src,
    const float* __restrict__ a_src1, const float* __restrict__ a_dst1,
    const float* __restrict__ h1, float* __restrict__ out1)
{
    const int wid = (blockIdx.x * 256 + threadIdx.x) >> 6;   // node id (wave-uniform)
    const int lane = threadIdx.x & 63;
    if (wid >= N_NODES) return;
    const int beg = rowptr[wid], end = rowptr[wid + 1];
    const float2 ad = *(const float2*)(a_dst1 + 2 * (size_t)wid);
    const int slot = lane >> 5, ch = lane & 31;
    const int head = ch >> 4;
    const float adh = head ? ad.y : ad.x;
    const int rep = ((ch & 15) == 0);
    float acc = 0.f, sw = 0.f;
    int i = beg + slot;
    // 4 edges in flight per lane (8 per wave with 2 slots): batch the loads
    for (; i + 6 < end; i += 8) {
        const int s0 = csr_src[i];
        const int s1 = csr_src[i + 2];
        const int s2 = csr_src[i + 4];
        const int s3 = csr_src[i + 6];
        const float a0 = a_src1[2 * (size_t)s0 + head];
        const float a1 = a_src1[2 * (size_t)s1 + head];
        const float a2 = a_src1[2 * (size_t)s2 + head];
        const float a3 = a_src1[2 * (size_t)s3 + head];
        const float h0 = h1[(size_t)s0 * 32 + ch];
        const float h1v = h1[(size_t)s1 * 32 + ch];
        const float h2v = h1[(size_t)s2 * 32 + ch];
        const float h3v = h1[(size_t)s3 * 32 + ch];
        const float w0 = __expf(lrelu(a0 + adh));
        const float w1 = __expf(lrelu(a1 + adh));
        const float w2 = __expf(lrelu(a2 + adh));
        const float w3 = __expf(lrelu(a3 + adh));
        if (rep) sw += (w0 + w1) + (w2 + w3);
        acc += w0 * h0 + w1 * h1v + w2 * h2v + w3 * h3v;
    }
    for (; i < end; i += 2) {
        const int s = csr_src[i];
        const float w = __expf(lrelu(a_src1[2 * (size_t)s + head] + adh));
        if (rep) sw += w;
        acc += w * h1[(size_t)s * 32 + ch];
    }
    // denom: combine even/odd halves per head (reps at lanes 0,16,32,48)
    sw += __shfl_xor(sw, 32);                    // lane0+=lane32, lane16+=lane48
    const float swh = __shfl(sw, head << 4);     // head0 <- lane0, head1 <- lane16
    acc += __shfl_xor(acc, 32);
    const float inv = 1.f / (swh + EPS_F);
    if (lane < 32) out1[(size_t)wid * 32 + lane] = acc * inv;
}

// ---------------- Kernel 4: h2 = elu(out1+b1) @ W2 ; a_src2/a_dst2 fused ----------------
__global__ __launch_bounds__(256) void k4_layer2(
    const float* __restrict__ out1, const float* __restrict__ b1,
    const float* __restrict__ W2, const float* __restrict__ att_src2,
    const float* __restrict__ att_dst2,
    float* __restrict__ h2, float* __restrict__ a_src2, float* __restrict__ a_dst2)
{
    __shared__ float act[16][32];
    __shared__ float w2s[32 * 16];
    __shared__ float b1s[32], as2[16], ad2[16];
    const int t = threadIdx.x;
    for (int i = t; i < 512; i += 256) w2s[i] = W2[i];
    if (t < 32) b1s[t] = b1[t];
    if (t < 16) { as2[t] = att_src2[t]; ad2[t] = att_dst2[t]; }
    __syncthreads();
    const int node0 = blockIdx.x * 16;
    for (int i = t; i < 512; i += 256) {
        const int nl = i >> 5, k = i & 31;
        const int row = node0 + nl;
        float v = 0.f;
        if (row < N_NODES) {
            v = out1[(size_t)row * 32 + k] + b1s[k];
            v = v > 0.f ? v : expm1f(v);
        }
        act[nl][k] = v;
    }
    __syncthreads();
    const int nl = t >> 4, j = t & 15;
    const int row = node0 + nl;
    float acc = 0.f;
    #pragma unroll
    for (int k = 0; k < 32; ++k) acc += act[nl][k] * w2s[k * 16 + j];
    if (row < N_NODES) h2[(size_t)row * 16 + j] = acc;
    float sa = acc * as2[j], sd = acc * ad2[j];
    #pragma unroll
    for (int m = 1; m < 16; m <<= 1) { sa += __shfl_xor(sa, m); sd += __shfl_xor(sd, m); }
    if (j == 0 && row < N_NODES) { a_src2[row] = sa; a_dst2[row] = sd; }
}

// -------- Layer-2 aggregation: deferred norm + 4-way MLP unroll --------
__global__ __launch_bounds__(256) void k_agg2(
    const int* __restrict__ rowptr, const int* __restrict__ csr_src,
    const float* __restrict__ a_src2, const float* __restrict__ a_dst2,
    const float* __restrict__ h2, float* __restrict__ out2)
{
    const int wid = (blockIdx.x * 256 + threadIdx.x) >> 6;
    const int lane = threadIdx.x & 63;
    if (wid >= N_NODES) return;
    const int beg = rowptr[wid], end = rowptr[wid + 1];
    const float ad = a_dst2[wid];
    const int slot = lane >> 4, ch = lane & 15;
    const int rep = (ch == 0);
    float acc = 0.f, sw = 0.f;
    int i = beg + slot;
    for (; i + 12 < end; i += 16) {
        const int s0 = csr_src[i];
        const int s1 = csr_src[i + 4];
        const int s2 = csr_src[i + 8];
        const int s3 = csr_src[i + 12];
        const float a0 = a_src2[s0];
        const float a1 = a_src2[s1];
        const float a2 = a_src2[s2];
        const float a3 = a_src2[s3];
        const float h0 = h2[(size_t)s0 * 16 + ch];
        const float h1v = h2[(size_t)s1 * 16 + ch];
        const float h2v = h2[(size_t)s2 * 16 + ch];
        const float h3v = h2[(size_t)s3 * 16 + ch];
        const float w0 = __expf(lrelu(a0 + ad));
        const float w1 = __expf(lrelu(a1 + ad));
        const float w2 = __expf(lrelu(a2 + ad));
        const float w3 = __expf(lrelu(a3 + ad));
        if (rep) sw += (w0 + w1) + (w2 + w3);
        acc += w0 * h0 + w1 * h1v + w2 * h2v + w3 * h3v;
    }
    for (; i < end; i += 4) {
        const int s = csr_src[i];
        const float w = __expf(lrelu(a_src2[s] + ad));
        if (rep) sw += w;
        acc += w * h2[(size_t)s * 16 + ch];
    }
    // denom: reps at lanes 0,16,32,48 hold quarter partials
    #pragma unroll
    for (int m = 1; m < 64; m <<= 1) sw += __shfl_xor(sw, m);
    acc += __shfl_xor(acc, 16);
    acc += __shfl_xor(acc, 32);
    const float inv = 1.f / (sw + EPS_F);
    if (lane < 16) out2[(size_t)wid * 16 + lane] = acc * inv;
}

// ---------------- Kernel 7: edge MLP (fp32 in/out) ----------------
__global__ __launch_bounds__(256) void k7_mlp(
    const int* __restrict__ ei, const int* __restrict__ flag,
    const float* __restrict__ out2, const float* __restrict__ b2,
    const float* __restrict__ Wm1, const float* __restrict__ bm1,
    const float* __restrict__ Wm2, const float* __restrict__ bm2,
    float* __restrict__ out)
{
    __shared__ float wm1s[32 * 16];
    __shared__ float b2s[16], bm1s[16], wm2s[16];
    __shared__ float bm2s;
    const int t = threadIdx.x;
    for (int i = t; i < 512; i += 256) wm1s[i] = Wm1[i];
    if (t < 16) { b2s[t] = b2[t]; bm1s[t] = bm1[t]; wm2s[t] = Wm2[t]; }
    if (t == 0) bm2s = bm2[0];
    __syncthreads();
    const int e = blockIdx.x * 256 + t;
    if (e >= N_EDGES) return;
    const int f = flag[0];
    const int s = ld_src(ei, f, e);
    const int d = ld_dst(ei, f, e);
    float hs[16], hd[16];
    const float4* sp = (const float4*)(out2 + (size_t)s * 16);
    const float4* dp = (const float4*)(out2 + (size_t)d * 16);
    #pragma unroll
    for (int i = 0; i < 4; ++i) {
        const float4 v = sp[i];
        hs[4 * i + 0] = v.x + b2s[4 * i + 0];
        hs[4 * i + 1] = v.y + b2s[4 * i + 1];
        hs[4 * i + 2] = v.z + b2s[4 * i + 2];
        hs[4 * i + 3] = v.w + b2s[4 * i + 3];
        const float4 u = dp[i];
        hd[4 * i + 0] = u.x + b2s[4 * i + 0];
        hd[4 * i + 1] = u.y + b2s[4 * i + 1];
        hd[4 * i + 2] = u.z + b2s[4 * i + 2];
        hd[4 * i + 3] = u.w + b2s[4 * i + 3];
    }
    float fl = bm2s;
    #pragma unroll
    for (int j = 0; j < 16; ++j) {
        float acc = bm1s[j];
        #pragma unroll
        for (int k = 0; k < 16; ++k) {
            acc += hs[k] * wm1s[k * 16 + j];
            acc += hd[k] * wm1s[(16 + k) * 16 + j];
        }
        acc = fmaxf(acc, 0.f);
        fl += acc * wm2s[j];
    }
    fl = fmaxf(fl, 0.f);
    out[e] = fl;
}

extern "C" void kernel_launch(void* const* d_in, const int* in_sizes, int n_in,
                              void* d_out, int out_size, void* d_ws, size_t ws_size,
                              hipStream_t stream)
{
    const float* x        = (const float*)d_in[0];
    const int*   ei       = (const int*)d_in[1];
    const float* W1       = (const float*)d_in[2];
    const float* att_src1 = (const float*)d_in[3];
    const float* att_dst1 = (const float*)d_in[4];
    const float* b1       = (const float*)d_in[5];
    const float* W2       = (const float*)d_in[6];
    const float* att_src2 = (const float*)d_in[7];
    const float* att_dst2 = (const float*)d_in[8];
    const float* b2       = (const float*)d_in[9];
    const float* Wm1      = (const float*)d_in[10];
    const float* bm1      = (const float*)d_in[11];
    const float* Wm2      = (const float*)d_in[12];
    const float* bm2      = (const float*)d_in[13];

    float* ws = (float*)d_ws;
    size_t off = 0;
    float* h1     = ws + off; off += 32 * (size_t)N_NODES;
    float* a_src1 = ws + off; off += 2  * (size_t)N_NODES;
    float* a_dst1 = ws + off; off += 2  * (size_t)N_NODES;
    float* out1   = ws + off; off += 32 * (size_t)N_NODES;
    float* h2     = ws + off; off += 16 * (size_t)N_NODES;
    float* a_src2 = ws + off; off += 1  * (size_t)N_NODES;
    float* a_dst2 = ws + off; off += 1  * (size_t)N_NODES;
    float* out2   = ws + off; off += 16 * (size_t)N_NODES;
    int* deg     = (int*)(ws + off); off += (size_t)N_NODES;
    int* locscan = (int*)(ws + off); off += (size_t)N_NODES;
    int* rowptr  = (int*)(ws + off); off += (size_t)N_NODES + 16;
    int* eoff    = (int*)(ws + off); off += (size_t)N_EDGES;
    int* csr_src = (int*)(ws + off); off += (size_t)N_EDGES;
    int* blksum  = (int*)(ws + off); off += 64;
    int* blkoff  = (int*)(ws + off); off += 64;
    int* flag    = (int*)(ws + off); off += 64;

    hipMemsetAsync(deg, 0, (size_t)N_NODES * sizeof(int), stream);

    k0_detect<<<1, 256, 0, stream>>>(ei, flag);
    k_deg<<<(N_EDGES + 255) / 256, 256, 0, stream>>>(ei, flag, deg, eoff);
    kscanA<<<N_SCAN_BLKS, SCAN_BLK, 0, stream>>>(deg, locscan, blksum);
    kscanB<<<1, 64, 0, stream>>>(blksum, blkoff, rowptr);
    kscanC<<<(N_NODES + 255) / 256, 256, 0, stream>>>(locscan, blkoff, rowptr);
    k_fill<<<(N_EDGES + 255) / 256, 256, 0, stream>>>(ei, flag, rowptr, eoff, csr_src);

    k1_gemm1<<<(N_NODES + 31) / 32, 256, 0, stream>>>(
        x, W1, att_src1, att_dst1, h1, a_src1, a_dst1);
    k_agg1<<<(N_NODES + 3) / 4, 256, 0, stream>>>(
        rowptr, csr_src, a_src1, a_dst1, h1, out1);
    k4_layer2<<<(N_NODES + 15) / 16, 256, 0, stream>>>(
        out1, b1, W2, att_src2, att_dst2, h2, a_src2, a_dst2);
    k_agg2<<<(N_NODES + 3) / 4, 256, 0, stream>>>(
        rowptr, csr_src, a_src2, a_dst2, h2, out2);
    k7_mlp<<<(N_EDGES + 255) / 256, 256, 0, stream>>>(
        ei, flag, out2, b2, Wm1, bm1, Wm2, bm2, (float*)d_out);
}

// Round 9
// 381.846 us; speedup vs baseline: 11.9433x; 1.0128x over previous
//
#include <hip/hip_runtime.h>
#include <hip/hip_bf16.h>

#define N_NODES 50000
#define N_EDGES 1600000
#define IN_CH 256
#define NEG_SLOPE 0.2f
#define EPS_F 1e-16f
#define SCAN_BLK 1024
#define N_SCAN_BLKS ((N_NODES + SCAN_BLK - 1) / SCAN_BLK)   // 49
#define DEG_PAD 16   // one 64B line per counter: kills cacheline-serialized atomics

__device__ __forceinline__ float lrelu(float x) {
    return x > 0.f ? x : NEG_SLOPE * x;
}

// -------- Kernel 0a: detect edge_index storage (int64 vs int32) --------
__global__ __launch_bounds__(256) void k0_detect(const int* __restrict__ ei,
                                                 int* __restrict__ flag)
{
    __shared__ int nz;
    const int t = threadIdx.x;
    if (t == 0) nz = 0;
    __syncthreads();
    if (t & 1) { if (ei[t] != 0) atomicAdd(&nz, 1); }
    __syncthreads();
    if (t == 0) flag[0] = (nz == 0) ? 1 : 0;   // 1 => int64 layout
}

__device__ __forceinline__ int ld_src(const int* ei, int f, int e) {
    return f ? ei[2 * (size_t)e] : ei[e];
}
__device__ __forceinline__ int ld_dst(const int* ei, int f, int e) {
    return f ? ei[2 * (size_t)N_EDGES + 2 * (size_t)e]
             : ei[(size_t)N_EDGES + e];
}

// -------- CSR build step 1: degree count (line-padded) + per-edge slot --------
__global__ __launch_bounds__(256) void k_deg(const int* __restrict__ ei,
                                             const int* __restrict__ flag,
                                             int* __restrict__ deg,
                                             int* __restrict__ eoff)
{
    const int e = blockIdx.x * 256 + threadIdx.x;
    if (e >= N_EDGES) return;
    const int f = flag[0];
    const int d = ld_dst(ei, f, e);
    eoff[e] = atomicAdd(&deg[(size_t)d * DEG_PAD], 1);
}

// -------- Hierarchical exclusive scan, phase A (reads padded deg) --------
__global__ __launch_bounds__(SCAN_BLK) void kscanA(const int* __restrict__ deg,
                                                   int* __restrict__ locscan,
                                                   int* __restrict__ blksum)
{
    __shared__ int wsum[SCAN_BLK / 64];
    const int t = threadIdx.x;
    const int i = blockIdx.x * SCAN_BLK + t;
    const int v = (i < N_NODES) ? deg[(size_t)i * DEG_PAD] : 0;
    const int lane = t & 63, w = t >> 6;
    int x = v;
    #pragma unroll
    for (int off = 1; off < 64; off <<= 1) {
        const int y = __shfl_up(x, off);
        if (lane >= off) x += y;
    }
    if (lane == 63) wsum[w] = x;
    __syncthreads();
    if (t < SCAN_BLK / 64) {
        const int wv = wsum[t];
        int xx = wv;
        #pragma unroll
        for (int off = 1; off < SCAN_BLK / 64; off <<= 1) {
            const int y = __shfl_up(xx, off);
            if (t >= off) xx += y;
        }
        wsum[t] = xx - wv;
    }
    __syncthreads();
    const int excl = x - v + wsum[w];
    if (i < N_NODES) locscan[i] = excl;
    if (t == SCAN_BLK - 1) blksum[blockIdx.x] = excl + v;
}

// -------- Phase B: scan block sums (one wave) --------
__global__ __launch_bounds__(64) void kscanB(const int* __restrict__ blksum,
                                             int* __restrict__ blkoff,
                                             int* __restrict__ rowptr)
{
    const int t = threadIdx.x;
    const int v = (t < N_SCAN_BLKS) ? blksum[t] : 0;
    int x = v;
    #pragma unroll
    for (int off = 1; off < 64; off <<= 1) {
        const int y = __shfl_up(x, off);
        if (t >= off) x += y;
    }
    if (t < N_SCAN_BLKS) blkoff[t] = x - v;
    if (t == 63) rowptr[N_NODES] = x;
}

// -------- Phase C: add block offsets --------
__global__ __launch_bounds__(256) void kscanC(const int* __restrict__ locscan,
                                              const int* __restrict__ blkoff,
                                              int* __restrict__ rowptr)
{
    const int i = blockIdx.x * 256 + threadIdx.x;
    if (i < N_NODES) rowptr[i] = locscan[i] + blkoff[i >> 10];
}

// -------- CSR build step 3: fill (no atomics) --------
__global__ __launch_bounds__(256) void k_fill(const int* __restrict__ ei,
                                              const int* __restrict__ flag,
                                              const int* __restrict__ rowptr,
                                              const int* __restrict__ eoff,
                                              int* __restrict__ csr_src)
{
    const int e = blockIdx.x * 256 + threadIdx.x;
    if (e >= N_EDGES) return;
    const int f = flag[0];
    const int s = ld_src(ei, f, e);
    const int d = ld_dst(ei, f, e);
    csr_src[rowptr[d] + eoff[e]] = s;
}

// ---------------- Kernel 1: h1 = x @ W1 ; a_src1/a_dst1 fused ----------------
// (R5-exact, proven)
__global__ __launch_bounds__(256) void k1_gemm1(
    const float* __restrict__ x, const float* __restrict__ W1,
    const float* __restrict__ att_src1, const float* __restrict__ att_dst1,
    float* __restrict__ h1, float* __restrict__ a_src1, float* __restrict__ a_dst1)
{
    __shared__ float w1s[IN_CH * 32];   // 32 KB
    __shared__ float xs[8][IN_CH];      // 8 KB
    __shared__ float attss[32], attds[32];
    const int t = threadIdx.x;
    for (int i = t; i < IN_CH * 32; i += 256) w1s[i] = W1[i];
    if (t < 32) { attss[t] = att_src1[t]; attds[t] = att_dst1[t]; }
    const int row0 = blockIdx.x * 32;
    const int col = t & 31, rl = t >> 5;
    for (int b = 0; b < 4; ++b) {
        const int rbase = row0 + b * 8;
        {
            const int r = t >> 5, chunk = t & 31;
            const int row = rbase + r;
            float4 v0 = make_float4(0.f, 0.f, 0.f, 0.f), v1 = v0;
            if (row < N_NODES) {
                const float4* p = (const float4*)(x + (size_t)row * IN_CH + chunk * 8);
                v0 = p[0]; v1 = p[1];
            }
            float* xp = &xs[r][chunk * 8];
            xp[0] = v0.x; xp[1] = v0.y; xp[2] = v0.z; xp[3] = v0.w;
            xp[4] = v1.x; xp[5] = v1.y; xp[6] = v1.z; xp[7] = v1.w;
        }
        __syncthreads();
        const int row = rbase + rl;
        float acc = 0.f;
        #pragma unroll 8
        for (int k = 0; k < IN_CH; ++k)
            acc += xs[rl][k] * w1s[k * 32 + col];
        if (row < N_NODES) h1[(size_t)row * 32 + col] = acc;
        const int head = col >> 4, c = col & 15;
        float sa = acc * attss[col];
        float sd = acc * attds[col];
        #pragma unroll
        for (int m = 1; m < 16; m <<= 1) {
            sa += __shfl_xor(sa, m);
            sd += __shfl_xor(sd, m);
        }
        if (c == 0 && row < N_NODES) {
            a_src1[row * 2 + head] = sa;
            a_dst1[row * 2 + head] = sd;
        }
        __syncthreads();
    }
}

// -------- Layer-1 aggregation: deferred norm + 4-way MLP unroll --------
__global__ __launch_bounds__(256) void k_agg1(
    const int* __restrict__ rowptr, const int* __restrict__ csr_src,
    const float* __restrict__ a_src1, const float* __restrict__ a_dst1,
    const float* __restrict__ h1, float* __restrict__ out1)
{
    const int wid = (blockIdx.x * 256 + threadIdx.x) >> 6;   // node id (wave-uniform)
    const int lane = threadIdx.x & 63;
    if (wid >= N_NODES) return;
    const int beg = rowptr[wid], end = rowptr[wid + 1];
    const float2 ad = *(const float2*)(a_dst1 + 2 * (size_t)wid);
    const int slot = lane >> 5, ch = lane & 31;
    const int head = ch >> 4;
    const float adh = head ? ad.y : ad.x;
    const int rep = ((ch & 15) == 0);
    float acc = 0.f, sw = 0.f;
    int i = beg + slot;
    // 4 edges in flight per lane (8 per wave with 2 slots): batch the loads
    for (; i + 6 < end; i += 8) {
        const int s0 = csr_src[i];
        const int s1 = csr_src[i + 2];
        const int s2 = csr_src[i + 4];
        const int s3 = csr_src[i + 6];
        const float a0 = a_src1[2 * (size_t)s0 + head];
        const float a1 = a_src1[2 * (size_t)s1 + head];
        const float a2 = a_src1[2 * (size_t)s2 + head];
        const float a3 = a_src1[2 * (size_t)s3 + head];
        const float h0 = h1[(size_t)s0 * 32 + ch];
        const float h1v = h1[(size_t)s1 * 32 + ch];
        const float h2v = h1[(size_t)s2 * 32 + ch];
        const float h3v = h1[(size_t)s3 * 32 + ch];
        const float w0 = __expf(lrelu(a0 + adh));
        const float w1 = __expf(lrelu(a1 + adh));
        const float w2 = __expf(lrelu(a2 + adh));
        const float w3 = __expf(lrelu(a3 + adh));
        if (rep) sw += (w0 + w1) + (w2 + w3);
        acc += w0 * h0 + w1 * h1v + w2 * h2v + w3 * h3v;
    }
    for (; i < end; i += 2) {
        const int s = csr_src[i];
        const float w = __expf(lrelu(a_src1[2 * (size_t)s + head] + adh));
        if (rep) sw += w;
        acc += w * h1[(size_t)s * 32 + ch];
    }
    // denom: combine even/odd halves per head (reps at lanes 0,16,32,48)
    sw += __shfl_xor(sw, 32);                    // lane0+=lane32, lane16+=lane48
    const float swh = __shfl(sw, head << 4);     // head0 <- lane0, head1 <- lane16
    acc += __shfl_xor(acc, 32);
    const float inv = 1.f / (swh + EPS_F);
    if (lane < 32) out1[(size_t)wid * 32 + lane] = acc * inv;
}

// ---------------- Kernel 4: h2 = elu(out1+b1) @ W2 ; a_src2/a_dst2 fused ----------------
__global__ __launch_bounds__(256) void k4_layer2(
    const float* __restrict__ out1, const float* __restrict__ b1,
    const float* __restrict__ W2, const float* __restrict__ att_src2,
    const float* __restrict__ att_dst2,
    float* __restrict__ h2, float* __restrict__ a_src2, float* __restrict__ a_dst2)
{
    __shared__ float act[16][32];
    __shared__ float w2s[32 * 16];
    __shared__ float b1s[32], as2[16], ad2[16];
    const int t = threadIdx.x;
    for (int i = t; i < 512; i += 256) w2s[i] = W2[i];
    if (t < 32) b1s[t] = b1[t];
    if (t < 16) { as2[t] = att_src2[t]; ad2[t] = att_dst2[t]; }
    __syncthreads();
    const int node0 = blockIdx.x * 16;
    for (int i = t; i < 512; i += 256) {
        const int nl = i >> 5, k = i & 31;
        const int row = node0 + nl;
        float v = 0.f;
        if (row < N_NODES) {
            v = out1[(size_t)row * 32 + k] + b1s[k];
            v = v > 0.f ? v : expm1f(v);
        }
        act[nl][k] = v;
    }
    __syncthreads();
    const int nl = t >> 4, j = t & 15;
    const int row = node0 + nl;
    float acc = 0.f;
    #pragma unroll
    for (int k = 0; k < 32; ++k) acc += act[nl][k] * w2s[k * 16 + j];
    if (row < N_NODES) h2[(size_t)row * 16 + j] = acc;
    float sa = acc * as2[j], sd = acc * ad2[j];
    #pragma unroll
    for (int m = 1; m < 16; m <<= 1) { sa += __shfl_xor(sa, m); sd += __shfl_xor(sd, m); }
    if (j == 0 && row < N_NODES) { a_src2[row] = sa; a_dst2[row] = sd; }
}

// -------- Layer-2 aggregation: deferred norm + 4-way MLP unroll --------
__global__ __launch_bounds__(256) void k_agg2(
    const int* __restrict__ rowptr, const int* __restrict__ csr_src,
    const float* __restrict__ a_src2, const float* __restrict__ a_dst2,
    const float* __restrict__ h2, float* __restrict__ out2)
{
    const int wid = (blockIdx.x * 256 + threadIdx.x) >> 6;
    const int lane = threadIdx.x & 63;
    if (wid >= N_NODES) return;
    const int beg = rowptr[wid], end = rowptr[wid + 1];
    const float ad = a_dst2[wid];
    const int slot = lane >> 4, ch = lane & 15;
    const int rep = (ch == 0);
    float acc = 0.f, sw = 0.f;
    int i = beg + slot;
    for (; i + 12 < end; i += 16) {
        const int s0 = csr_src[i];
        const int s1 = csr_src[i + 4];
        const int s2 = csr_src[i + 8];
        const int s3 = csr_src[i + 12];
        const float a0 = a_src2[s0];
        const float a1 = a_src2[s1];
        const float a2 = a_src2[s2];
        const float a3 = a_src2[s3];
        const float h0 = h2[(size_t)s0 * 16 + ch];
        const float h1v = h2[(size_t)s1 * 16 + ch];
        const float h2v = h2[(size_t)s2 * 16 + ch];
        const float h3v = h2[(size_t)s3 * 16 + ch];
        const float w0 = __expf(lrelu(a0 + ad));
        const float w1 = __expf(lrelu(a1 + ad));
        const float w2 = __expf(lrelu(a2 + ad));
        const float w3 = __expf(lrelu(a3 + ad));
        if (rep) sw += (w0 + w1) + (w2 + w3);
        acc += w0 * h0 + w1 * h1v + w2 * h2v + w3 * h3v;
    }
    for (; i < end; i += 4) {
        const int s = csr_src[i];
        const float w = __expf(lrelu(a_src2[s] + ad));
        if (rep) sw += w;
        acc += w * h2[(size_t)s * 16 + ch];
    }
    // denom: reps at lanes 0,16,32,48 hold quarter partials
    #pragma unroll
    for (int m = 1; m < 64; m <<= 1) sw += __shfl_xor(sw, m);
    acc += __shfl_xor(acc, 16);
    acc += __shfl_xor(acc, 32);
    const float inv = 1.f / (sw + EPS_F);
    if (lane < 16) out2[(size_t)wid * 16 + lane] = acc * inv;
}

// ---------------- Kernel 7: edge MLP (fp32 in/out) ----------------
__global__ __launch_bounds__(256) void k7_mlp(
    const int* __restrict__ ei, const int* __restrict__ flag,
    const float* __restrict__ out2, const float* __restrict__ b2,
    const float* __restrict__ Wm1, const float* __restrict__ bm1,
    const float* __restrict__ Wm2, const float* __restrict__ bm2,
    float* __restrict__ out)
{
    __shared__ float wm1s[32 * 16];
    __shared__ float b2s[16], bm1s[16], wm2s[16];
    __shared__ float bm2s;
    const int t = threadIdx.x;
    for (int i = t; i < 512; i += 256) wm1s[i] = Wm1[i];
    if (t < 16) { b2s[t] = b2[t]; bm1s[t] = bm1[t]; wm2s[t] = Wm2[t]; }
    if (t == 0) bm2s = bm2[0];
    __syncthreads();
    const int e = blockIdx.x * 256 + t;
    if (e >= N_EDGES) return;
    const int f = flag[0];
    const int s = ld_src(ei, f, e);
    const int d = ld_dst(ei, f, e);
    float hs[16], hd[16];
    const float4* sp = (const float4*)(out2 + (size_t)s * 16);
    const float4* dp = (const float4*)(out2 + (size_t)d * 16);
    #pragma unroll
    for (int i = 0; i < 4; ++i) {
        const float4 v = sp[i];
        hs[4 * i + 0] = v.x + b2s[4 * i + 0];
        hs[4 * i + 1] = v.y + b2s[4 * i + 1];
        hs[4 * i + 2] = v.z + b2s[4 * i + 2];
        hs[4 * i + 3] = v.w + b2s[4 * i + 3];
        const float4 u = dp[i];
        hd[4 * i + 0] = u.x + b2s[4 * i + 0];
        hd[4 * i + 1] = u.y + b2s[4 * i + 1];
        hd[4 * i + 2] = u.z + b2s[4 * i + 2];
        hd[4 * i + 3] = u.w + b2s[4 * i + 3];
    }
    float fl = bm2s;
    #pragma unroll
    for (int j = 0; j < 16; ++j) {
        float acc = bm1s[j];
        #pragma unroll
        for (int k = 0; k < 16; ++k) {
            acc += hs[k] * wm1s[k * 16 + j];
            acc += hd[k] * wm1s[(16 + k) * 16 + j];
        }
        acc = fmaxf(acc, 0.f);
        fl += acc * wm2s[j];
    }
    fl = fmaxf(fl, 0.f);
    out[e] = fl;
}

extern "C" void kernel_launch(void* const* d_in, const int* in_sizes, int n_in,
                              void* d_out, int out_size, void* d_ws, size_t ws_size,
                              hipStream_t stream)
{
    const float* x        = (const float*)d_in[0];
    const int*   ei       = (const int*)d_in[1];
    const float* W1       = (const float*)d_in[2];
    const float* att_src1 = (const float*)d_in[3];
    const float* att_dst1 = (const float*)d_in[4];
    const float* b1       = (const float*)d_in[5];
    const float* W2       = (const float*)d_in[6];
    const float* att_src2 = (const float*)d_in[7];
    const float* att_dst2 = (const float*)d_in[8];
    const float* b2       = (const float*)d_in[9];
    const float* Wm1      = (const float*)d_in[10];
    const float* bm1      = (const float*)d_in[11];
    const float* Wm2      = (const float*)d_in[12];
    const float* bm2      = (const float*)d_in[13];

    float* ws = (float*)d_ws;
    size_t off = 0;
    float* h1     = ws + off; off += 32 * (size_t)N_NODES;
    float* a_src1 = ws + off; off += 2  * (size_t)N_NODES;
    float* a_dst1 = ws + off; off += 2  * (size_t)N_NODES;
    float* out1   = ws + off; off += 32 * (size_t)N_NODES;
    float* h2     = ws + off; off += 16 * (size_t)N_NODES;
    float* a_src2 = ws + off; off += 1  * (size_t)N_NODES;
    float* a_dst2 = ws + off; off += 1  * (size_t)N_NODES;
    float* out2   = ws + off; off += 16 * (size_t)N_NODES;
    int* deg     = (int*)(ws + off); off += (size_t)N_NODES * DEG_PAD;   // padded: 1 counter / 64B line
    int* locscan = (int*)(ws + off); off += (size_t)N_NODES;
    int* rowptr  = (int*)(ws + off); off += (size_t)N_NODES + 16;
    int* eoff    = (int*)(ws + off); off += (size_t)N_EDGES;
    int* csr_src = (int*)(ws + off); off += (size_t)N_EDGES;
    int* blksum  = (int*)(ws + off); off += 64;
    int* blkoff  = (int*)(ws + off); off += 64;
    int* flag    = (int*)(ws + off); off += 64;

    hipMemsetAsync(deg, 0, (size_t)N_NODES * DEG_PAD * sizeof(int), stream);

    k0_detect<<<1, 256, 0, stream>>>(ei, flag);
    k_deg<<<(N_EDGES + 255) / 256, 256, 0, stream>>>(ei, flag, deg, eoff);
    kscanA<<<N_SCAN_BLKS, SCAN_BLK, 0, stream>>>(deg, locscan, blksum);
    kscanB<<<1, 64, 0, stream>>>(blksum, blkoff, rowptr);
    kscanC<<<(N_NODES + 255) / 256, 256, 0, stream>>>(locscan, blkoff, rowptr);
    k_fill<<<(N_EDGES + 255) / 256, 256, 0, stream>>>(ei, flag, rowptr, eoff, csr_src);

    k1_gemm1<<<(N_NODES + 31) / 32, 256, 0, stream>>>(
        x, W1, att_src1, att_dst1, h1, a_src1, a_dst1);
    k_agg1<<<(N_NODES + 3) / 4, 256, 0, stream>>>(
        rowptr, csr_src, a_src1, a_dst1, h1, out1);
    k4_layer2<<<(N_NODES + 15) / 16, 256, 0, stream>>>(
        out1, b1, W2, att_src2, att_dst2, h2, a_src2, a_dst2);
    k_agg2<<<(N_NODES + 3) / 4, 256, 0, stream>>>(
        rowptr, csr_src, a_src2, a_dst2, h2, out2);
    k7_mlp<<<(N_EDGES + 255) / 256, 256, 0, stream>>>(
        ei, flag, out2, b2, Wm1, bm1, Wm2, bm2, (float*)d_out);
}

// Round 10
// 370.967 us; speedup vs baseline: 12.2935x; 1.0293x over previous
//
#include <hip/hip_runtime.h>
#include <hip/hip_bf16.h>

#define N_NODES 50000
#define N_EDGES 1600000
#define IN_CH 256
#define NEG_SLOPE 0.2f
#define EPS_F 1e-16f
#define SCAN_BLK 1024
#define N_SCAN_BLKS ((N_NODES + SCAN_BLK - 1) / SCAN_BLK)   // 49
#define DEG_PAD 16   // one 64B line per counter: kills cacheline-serialized atomics

__device__ __forceinline__ float lrelu(float x) {
    return x > 0.f ? x : NEG_SLOPE * x;
}

// -------- Kernel 0a: detect edge_index storage (int64 vs int32) --------
__global__ __launch_bounds__(256) void k0_detect(const int* __restrict__ ei,
                                                 int* __restrict__ flag)
{
    __shared__ int nz;
    const int t = threadIdx.x;
    if (t == 0) nz = 0;
    __syncthreads();
    if (t & 1) { if (ei[t] != 0) atomicAdd(&nz, 1); }
    __syncthreads();
    if (t == 0) flag[0] = (nz == 0) ? 1 : 0;   // 1 => int64 layout
}

__device__ __forceinline__ int ld_src(const int* ei, int f, int e) {
    return f ? ei[2 * (size_t)e] : ei[e];
}
__device__ __forceinline__ int ld_dst(const int* ei, int f, int e) {
    return f ? ei[2 * (size_t)N_EDGES + 2 * (size_t)e]
             : ei[(size_t)N_EDGES + e];
}

// -------- CSR build step 1: degree count (line-padded) + per-edge slot --------
__global__ __launch_bounds__(256) void k_deg(const int* __restrict__ ei,
                                             const int* __restrict__ flag,
                                             int* __restrict__ deg,
                                             int* __restrict__ eoff)
{
    const int e = blockIdx.x * 256 + threadIdx.x;
    if (e >= N_EDGES) return;
    const int f = flag[0];
    const int d = ld_dst(ei, f, e);
    eoff[e] = atomicAdd(&deg[(size_t)d * DEG_PAD], 1);
}

// -------- Hierarchical exclusive scan, phase A (reads padded deg) --------
__global__ __launch_bounds__(SCAN_BLK) void kscanA(const int* __restrict__ deg,
                                                   int* __restrict__ locscan,
                                                   int* __restrict__ blksum)
{
    __shared__ int wsum[SCAN_BLK / 64];
    const int t = threadIdx.x;
    const int i = blockIdx.x * SCAN_BLK + t;
    const int v = (i < N_NODES) ? deg[(size_t)i * DEG_PAD] : 0;
    const int lane = t & 63, w = t >> 6;
    int x = v;
    #pragma unroll
    for (int off = 1; off < 64; off <<= 1) {
        const int y = __shfl_up(x, off);
        if (lane >= off) x += y;
    }
    if (lane == 63) wsum[w] = x;
    __syncthreads();
    if (t < SCAN_BLK / 64) {
        const int wv = wsum[t];
        int xx = wv;
        #pragma unroll
        for (int off = 1; off < SCAN_BLK / 64; off <<= 1) {
            const int y = __shfl_up(xx, off);
            if (t >= off) xx += y;
        }
        wsum[t] = xx - wv;
    }
    __syncthreads();
    const int excl = x - v + wsum[w];
    if (i < N_NODES) locscan[i] = excl;
    if (t == SCAN_BLK - 1) blksum[blockIdx.x] = excl + v;
}

// -------- Phase B: scan block sums (one wave) --------
__global__ __launch_bounds__(64) void kscanB(const int* __restrict__ blksum,
                                             int* __restrict__ blkoff,
                                             int* __restrict__ rowptr)
{
    const int t = threadIdx.x;
    const int v = (t < N_SCAN_BLKS) ? blksum[t] : 0;
    int x = v;
    #pragma unroll
    for (int off = 1; off < 64; off <<= 1) {
        const int y = __shfl_up(x, off);
        if (t >= off) x += y;
    }
    if (t < N_SCAN_BLKS) blkoff[t] = x - v;
    if (t == 63) rowptr[N_NODES] = x;
}

// -------- Phase C: add block offsets --------
__global__ __launch_bounds__(256) void kscanC(const int* __restrict__ locscan,
                                              const int* __restrict__ blkoff,
                                              int* __restrict__ rowptr)
{
    const int i = blockIdx.x * 256 + threadIdx.x;
    if (i < N_NODES) rowptr[i] = locscan[i] + blkoff[i >> 10];
}

// -------- CSR build step 3: fill (no atomics) --------
__global__ __launch_bounds__(256) void k_fill(const int* __restrict__ ei,
                                              const int* __restrict__ flag,
                                              const int* __restrict__ rowptr,
                                              const int* __restrict__ eoff,
                                              int* __restrict__ csr_src)
{
    const int e = blockIdx.x * 256 + threadIdx.x;
    if (e >= N_EDGES) return;
    const int f = flag[0];
    const int s = ld_src(ei, f, e);
    const int d = ld_dst(ei, f, e);
    csr_src[rowptr[d] + eoff[e]] = s;
}

// ---------------- Kernel 1: h1 = x @ W1 ; a_src1/a_dst1 fused ----------------
// (R5-exact, proven)
__global__ __launch_bounds__(256) void k1_gemm1(
    const float* __restrict__ x, const float* __restrict__ W1,
    const float* __restrict__ att_src1, const float* __restrict__ att_dst1,
    float* __restrict__ h1, float* __restrict__ a_src1, float* __restrict__ a_dst1)
{
    __shared__ float w1s[IN_CH * 32];   // 32 KB
    __shared__ float xs[8][IN_CH];      // 8 KB
    __shared__ float attss[32], attds[32];
    const int t = threadIdx.x;
    for (int i = t; i < IN_CH * 32; i += 256) w1s[i] = W1[i];
    if (t < 32) { attss[t] = att_src1[t]; attds[t] = att_dst1[t]; }
    const int row0 = blockIdx.x * 32;
    const int col = t & 31, rl = t >> 5;
    for (int b = 0; b < 4; ++b) {
        const int rbase = row0 + b * 8;
        {
            const int r = t >> 5, chunk = t & 31;
            const int row = rbase + r;
            float4 v0 = make_float4(0.f, 0.f, 0.f, 0.f), v1 = v0;
            if (row < N_NODES) {
                const float4* p = (const float4*)(x + (size_t)row * IN_CH + chunk * 8);
                v0 = p[0]; v1 = p[1];
            }
            float* xp = &xs[r][chunk * 8];
            xp[0] = v0.x; xp[1] = v0.y; xp[2] = v0.z; xp[3] = v0.w;
            xp[4] = v1.x; xp[5] = v1.y; xp[6] = v1.z; xp[7] = v1.w;
        }
        __syncthreads();
        const int row = rbase + rl;
        float acc = 0.f;
        #pragma unroll 8
        for (int k = 0; k < IN_CH; ++k)
            acc += xs[rl][k] * w1s[k * 32 + col];
        if (row < N_NODES) h1[(size_t)row * 32 + col] = acc;
        const int head = col >> 4, c = col & 15;
        float sa = acc * attss[col];
        float sd = acc * attds[col];
        #pragma unroll
        for (int m = 1; m < 16; m <<= 1) {
            sa += __shfl_xor(sa, m);
            sd += __shfl_xor(sd, m);
        }
        if (c == 0 && row < N_NODES) {
            a_src1[row * 2 + head] = sa;
            a_dst1[row * 2 + head] = sd;
        }
        __syncthreads();
    }
}

// -------- Layer-1 aggregation: deferred norm + 4-way MLP unroll --------
__global__ __launch_bounds__(256) void k_agg1(
    const int* __restrict__ rowptr, const int* __restrict__ csr_src,
    const float* __restrict__ a_src1, const float* __restrict__ a_dst1,
    const float* __restrict__ h1, float* __restrict__ out1)
{
    const int wid = (blockIdx.x * 256 + threadIdx.x) >> 6;   // node id (wave-uniform)
    const int lane = threadIdx.x & 63;
    if (wid >= N_NODES) return;
    const int beg = rowptr[wid], end = rowptr[wid + 1];
    const float2 ad = *(const float2*)(a_dst1 + 2 * (size_t)wid);
    const int slot = lane >> 5, ch = lane & 31;
    const int head = ch >> 4;
    const float adh = head ? ad.y : ad.x;
    const int rep = ((ch & 15) == 0);
    float acc = 0.f, sw = 0.f;
    int i = beg + slot;
    for (; i + 6 < end; i += 8) {
        const int s0 = csr_src[i];
        const int s1 = csr_src[i + 2];
        const int s2 = csr_src[i + 4];
        const int s3 = csr_src[i + 6];
        const float a0 = a_src1[2 * (size_t)s0 + head];
        const float a1 = a_src1[2 * (size_t)s1 + head];
        const float a2 = a_src1[2 * (size_t)s2 + head];
        const float a3 = a_src1[2 * (size_t)s3 + head];
        const float h0 = h1[(size_t)s0 * 32 + ch];
        const float h1v = h1[(size_t)s1 * 32 + ch];
        const float h2v = h1[(size_t)s2 * 32 + ch];
        const float h3v = h1[(size_t)s3 * 32 + ch];
        const float w0 = __expf(lrelu(a0 + adh));
        const float w1 = __expf(lrelu(a1 + adh));
        const float w2 = __expf(lrelu(a2 + adh));
        const float w3 = __expf(lrelu(a3 + adh));
        if (rep) sw += (w0 + w1) + (w2 + w3);
        acc += w0 * h0 + w1 * h1v + w2 * h2v + w3 * h3v;
    }
    for (; i < end; i += 2) {
        const int s = csr_src[i];
        const float w = __expf(lrelu(a_src1[2 * (size_t)s + head] + adh));
        if (rep) sw += w;
        acc += w * h1[(size_t)s * 32 + ch];
    }
    sw += __shfl_xor(sw, 32);
    const float swh = __shfl(sw, head << 4);
    acc += __shfl_xor(acc, 32);
    const float inv = 1.f / (swh + EPS_F);
    if (lane < 32) out1[(size_t)wid * 32 + lane] = acc * inv;
}

// ---------------- Kernel 4: h2 = elu(out1+b1) @ W2 ; a_src2/a_dst2 fused ----------------
__global__ __launch_bounds__(256) void k4_layer2(
    const float* __restrict__ out1, const float* __restrict__ b1,
    const float* __restrict__ W2, const float* __restrict__ att_src2,
    const float* __restrict__ att_dst2,
    float* __restrict__ h2, float* __restrict__ a_src2, float* __restrict__ a_dst2)
{
    __shared__ float act[16][32];
    __shared__ float w2s[32 * 16];
    __shared__ float b1s[32], as2[16], ad2[16];
    const int t = threadIdx.x;
    for (int i = t; i < 512; i += 256) w2s[i] = W2[i];
    if (t < 32) b1s[t] = b1[t];
    if (t < 16) { as2[t] = att_src2[t]; ad2[t] = att_dst2[t]; }
    __syncthreads();
    const int node0 = blockIdx.x * 16;
    for (int i = t; i < 512; i += 256) {
        const int nl = i >> 5, k = i & 31;
        const int row = node0 + nl;
        float v = 0.f;
        if (row < N_NODES) {
            v = out1[(size_t)row * 32 + k] + b1s[k];
            v = v > 0.f ? v : expm1f(v);
        }
        act[nl][k] = v;
    }
    __syncthreads();
    const int nl = t >> 4, j = t & 15;
    const int row = node0 + nl;
    float acc = 0.f;
    #pragma unroll
    for (int k = 0; k < 32; ++k) acc += act[nl][k] * w2s[k * 16 + j];
    if (row < N_NODES) h2[(size_t)row * 16 + j] = acc;
    float sa = acc * as2[j], sd = acc * ad2[j];
    #pragma unroll
    for (int m = 1; m < 16; m <<= 1) { sa += __shfl_xor(sa, m); sd += __shfl_xor(sd, m); }
    if (j == 0 && row < N_NODES) { a_src2[row] = sa; a_dst2[row] = sd; }
}

// -------- Layer-2 aggregation: deferred norm + 4-way MLP unroll --------
__global__ __launch_bounds__(256) void k_agg2(
    const int* __restrict__ rowptr, const int* __restrict__ csr_src,
    const float* __restrict__ a_src2, const float* __restrict__ a_dst2,
    const float* __restrict__ h2, float* __restrict__ out2)
{
    const int wid = (blockIdx.x * 256 + threadIdx.x) >> 6;
    const int lane = threadIdx.x & 63;
    if (wid >= N_NODES) return;
    const int beg = rowptr[wid], end = rowptr[wid + 1];
    const float ad = a_dst2[wid];
    const int slot = lane >> 4, ch = lane & 15;
    const int rep = (ch == 0);
    float acc = 0.f, sw = 0.f;
    int i = beg + slot;
    for (; i + 12 < end; i += 16) {
        const int s0 = csr_src[i];
        const int s1 = csr_src[i + 4];
        const int s2 = csr_src[i + 8];
        const int s3 = csr_src[i + 12];
        const float a0 = a_src2[s0];
        const float a1 = a_src2[s1];
        const float a2 = a_src2[s2];
        const float a3 = a_src2[s3];
        const float h0 = h2[(size_t)s0 * 16 + ch];
        const float h1v = h2[(size_t)s1 * 16 + ch];
        const float h2v = h2[(size_t)s2 * 16 + ch];
        const float h3v = h2[(size_t)s3 * 16 + ch];
        const float w0 = __expf(lrelu(a0 + ad));
        const float w1 = __expf(lrelu(a1 + ad));
        const float w2 = __expf(lrelu(a2 + ad));
        const float w3 = __expf(lrelu(a3 + ad));
        if (rep) sw += (w0 + w1) + (w2 + w3);
        acc += w0 * h0 + w1 * h1v + w2 * h2v + w3 * h3v;
    }
    for (; i < end; i += 4) {
        const int s = csr_src[i];
        const float w = __expf(lrelu(a_src2[s] + ad));
        if (rep) sw += w;
        acc += w * h2[(size_t)s * 16 + ch];
    }
    #pragma unroll
    for (int m = 1; m < 64; m <<= 1) sw += __shfl_xor(sw, m);
    acc += __shfl_xor(acc, 16);
    acc += __shfl_xor(acc, 32);
    const float inv = 1.f / (sw + EPS_F);
    if (lane < 16) out2[(size_t)wid * 16 + lane] = acc * inv;
}

// -------- k_prep: hoist edge-MLP first layer to nodes --------
// u[n][j] = bm1[j] + sum_k (out2[n][k]+b2[k]) * Wm1[k][j]        (src half)
// v[n][j] =          sum_k (out2[n][k]+b2[k]) * Wm1[16+k][j]     (dst half)
__global__ __launch_bounds__(256) void k_prep(
    const float* __restrict__ out2, const float* __restrict__ b2,
    const float* __restrict__ Wm1, const float* __restrict__ bm1,
    float* __restrict__ u, float* __restrict__ v)
{
    __shared__ float wa[16 * 16], wb[16 * 16];
    __shared__ float act[16][17];
    __shared__ float b2s[16], bm1s[16];
    const int t = threadIdx.x;
    if (t < 256) {
        const int k = t >> 4, j = t & 15;
        wa[t] = Wm1[k * 16 + j];
        wb[t] = Wm1[(16 + k) * 16 + j];
    }
    if (t < 16) { b2s[t] = b2[t]; bm1s[t] = bm1[t]; }
    __syncthreads();
    const int node0 = blockIdx.x * 16;
    const int nl = t >> 4, c = t & 15;
    const int row = node0 + nl;
    act[nl][c] = (row < N_NODES) ? out2[(size_t)row * 16 + c] + b2s[c] : 0.f;
    __syncthreads();
    float su = bm1s[c], sv = 0.f;
    #pragma unroll
    for (int k = 0; k < 16; ++k) {
        const float a = act[nl][k];
        su += a * wa[k * 16 + c];
        sv += a * wb[k * 16 + c];
    }
    if (row < N_NODES) {
        u[(size_t)row * 16 + c] = su;
        v[(size_t)row * 16 + c] = sv;
    }
}

// ---------------- Kernel 7 lite: per-edge tail of the MLP ----------------
// fl = relu( bm2 + sum_j relu(u[s][j] + v[d][j]) * wm2[j] )
__global__ __launch_bounds__(256) void k7_lite(
    const int* __restrict__ ei, const int* __restrict__ flag,
    const float* __restrict__ u, const float* __restrict__ v,
    const float* __restrict__ Wm2, const float* __restrict__ bm2,
    float* __restrict__ out)
{
    __shared__ float wm2s[16];
    __shared__ float bm2s;
    const int t = threadIdx.x;
    if (t < 16) wm2s[t] = Wm2[t];
    if (t == 0) bm2s = bm2[0];
    __syncthreads();
    const int e = blockIdx.x * 256 + t;
    if (e >= N_EDGES) return;
    const int f = flag[0];
    const int s = ld_src(ei, f, e);
    const int d = ld_dst(ei, f, e);
    const float4* up = (const float4*)(u + (size_t)s * 16);
    const float4* vp = (const float4*)(v + (size_t)d * 16);
    float fl = bm2s;
    #pragma unroll
    for (int i = 0; i < 4; ++i) {
        const float4 a = up[i];
        const float4 b = vp[i];
        fl += fmaxf(a.x + b.x, 0.f) * wm2s[4 * i + 0];
        fl += fmaxf(a.y + b.y, 0.f) * wm2s[4 * i + 1];
        fl += fmaxf(a.z + b.z, 0.f) * wm2s[4 * i + 2];
        fl += fmaxf(a.w + b.w, 0.f) * wm2s[4 * i + 3];
    }
    out[e] = fmaxf(fl, 0.f);
}

extern "C" void kernel_launch(void* const* d_in, const int* in_sizes, int n_in,
                              void* d_out, int out_size, void* d_ws, size_t ws_size,
                              hipStream_t stream)
{
    const float* x        = (const float*)d_in[0];
    const int*   ei       = (const int*)d_in[1];
    const float* W1       = (const float*)d_in[2];
    const float* att_src1 = (const float*)d_in[3];
    const float* att_dst1 = (const float*)d_in[4];
    const float* b1       = (const float*)d_in[5];
    const float* W2       = (const float*)d_in[6];
    const float* att_src2 = (const float*)d_in[7];
    const float* att_dst2 = (const float*)d_in[8];
    const float* b2       = (const float*)d_in[9];
    const float* Wm1      = (const float*)d_in[10];
    const float* bm1      = (const float*)d_in[11];
    const float* Wm2      = (const float*)d_in[12];
    const float* bm2      = (const float*)d_in[13];

    float* ws = (float*)d_ws;
    size_t off = 0;
    float* h1     = ws + off; off += 32 * (size_t)N_NODES;
    float* a_src1 = ws + off; off += 2  * (size_t)N_NODES;
    float* a_dst1 = ws + off; off += 2  * (size_t)N_NODES;
    float* out1   = ws + off; off += 32 * (size_t)N_NODES;
    float* h2     = ws + off; off += 16 * (size_t)N_NODES;
    float* a_src2 = ws + off; off += 1  * (size_t)N_NODES;
    float* a_dst2 = ws + off; off += 1  * (size_t)N_NODES;
    float* out2   = ws + off; off += 16 * (size_t)N_NODES;
    float* u      = ws + off; off += 16 * (size_t)N_NODES;
    float* v      = ws + off; off += 16 * (size_t)N_NODES;
    int* deg     = (int*)(ws + off); off += (size_t)N_NODES * DEG_PAD;
    int* locscan = (int*)(ws + off); off += (size_t)N_NODES;
    int* rowptr  = (int*)(ws + off); off += (size_t)N_NODES + 16;
    int* eoff    = (int*)(ws + off); off += (size_t)N_EDGES;
    int* csr_src = (int*)(ws + off); off += (size_t)N_EDGES;
    int* blksum  = (int*)(ws + off); off += 64;
    int* blkoff  = (int*)(ws + off); off += 64;
    int* flag    = (int*)(ws + off); off += 64;

    hipMemsetAsync(deg, 0, (size_t)N_NODES * DEG_PAD * sizeof(int), stream);

    k0_detect<<<1, 256, 0, stream>>>(ei, flag);
    k_deg<<<(N_EDGES + 255) / 256, 256, 0, stream>>>(ei, flag, deg, eoff);
    kscanA<<<N_SCAN_BLKS, SCAN_BLK, 0, stream>>>(deg, locscan, blksum);
    kscanB<<<1, 64, 0, stream>>>(blksum, blkoff, rowptr);
    kscanC<<<(N_NODES + 255) / 256, 256, 0, stream>>>(locscan, blkoff, rowptr);
    k_fill<<<(N_EDGES + 255) / 256, 256, 0, stream>>>(ei, flag, rowptr, eoff, csr_src);

    k1_gemm1<<<(N_NODES + 31) / 32, 256, 0, stream>>>(
        x, W1, att_src1, att_dst1, h1, a_src1, a_dst1);
    k_agg1<<<(N_NODES + 3) / 4, 256, 0, stream>>>(
        rowptr, csr_src, a_src1, a_dst1, h1, out1);
    k4_layer2<<<(N_NODES + 15) / 16, 256, 0, stream>>>(
        out1, b1, W2, att_src2, att_dst2, h2, a_src2, a_dst2);
    k_agg2<<<(N_NODES + 3) / 4, 256, 0, stream>>>(
        rowptr, csr_src, a_src2, a_dst2, h2, out2);
    k_prep<<<(N_NODES + 15) / 16, 256, 0, stream>>>(
        out2, b2, Wm1, bm1, u, v);
    k7_lite<<<(N_EDGES + 255) / 256, 256, 0, stream>>>(
        ei, flag, u, v, Wm2, bm2, (float*)d_out);
}